// Round 6
// baseline (1014.797 us; speedup 1.0000x reference)
//
#include <hip/hip_runtime.h>
#include <math.h>

// Problem constants: B=4, T=8, C=d=256, H=W=48, L=2, nh=8, dk=32
#define SEQ   9216          // B*H*W
#define TOK   73728         // SEQ*T

typedef short bf16x8 __attribute__((ext_vector_type(8)));
typedef short bf16x4 __attribute__((ext_vector_type(4)));
typedef float f32x4  __attribute__((ext_vector_type(4)));

#define GLD_LDS16(gsrc, ldst)                                                      \
    __builtin_amdgcn_global_load_lds(                                              \
        (const __attribute__((address_space(1))) unsigned int*)(gsrc),             \
        (__attribute__((address_space(3))) unsigned int*)(ldst), 16, 0, 0)

__device__ __forceinline__ unsigned short f2bf(float f) {
    unsigned u = __builtin_bit_cast(unsigned, f);
    unsigned r = (u + 0x7fffu + ((u >> 16) & 1u)) >> 16;
    return (unsigned short)r;
}
__device__ __forceinline__ float bf2f(unsigned short h) {
    return __builtin_bit_cast(float, (unsigned)h << 16);
}

// ---------------------------------------------------------------------------
__global__ void pe_fill(float* __restrict__ pe) {
    int idx = blockIdx.x * 256 + threadIdx.x;   // 0..2047
    int t = idx >> 8, c = idx & 255;
    int i2 = c & ~1;
    float div = __expf((float)i2 * (-logf(10000.f) / 256.f));
    float ang = (float)t * div;
    pe[idx] = (c & 1) ? cosf(ang) : sinf(ang);
}

__global__ void convertw(const float* __restrict__ src, unsigned short* __restrict__ dst, int n4) {
    int i = blockIdx.x * 256 + threadIdx.x;
    if (i < n4) {
        float4 v = *(const float4*)(src + (size_t)i * 4);
        unsigned short* o = dst + (size_t)i * 4;
        o[0] = f2bf(v.x); o[1] = f2bf(v.y); o[2] = f2bf(v.z); o[3] = f2bf(v.w);
    }
}

__global__ void pack_bias(const float* __restrict__ bq, const float* __restrict__ bk,
                          const float* __restrict__ bv, float* __restrict__ dst) {
    int l = blockIdx.x, i = threadIdx.x;        // block = 768 threads
    float v = (i < 256) ? bq[l * 256 + i] : (i < 512) ? bk[l * 256 + i - 256]
                                                      : bv[l * 256 + i - 512];
    dst[l * 768 + i] = v;
}

// ---------------------------------------------------------------------------
// x (B,T,C,H,W) -> h (n, t, c) fp32 AND hb bf16, with += pe[t,c].
__global__ __launch_bounds__(256) void transpose_in(const float* __restrict__ x,
                                                    const float* __restrict__ pe,
                                                    float* __restrict__ h,
                                                    unsigned short* __restrict__ hb) {
    int bty = blockIdx.x;
    int y = bty % 48; int bt = bty / 48; int t = bt & 7; int b = bt >> 3;
    int c0 = blockIdx.y * 32, w0 = blockIdx.z * 32;
    __shared__ float tile[32][33];
    int tid = threadIdx.x;
    const float* xp = x + ((size_t)(b * 8 + t) * 256) * 2304 + (size_t)y * 48;
    int wl = tid & 31, cl8 = tid >> 5;
#pragma unroll
    for (int it = 0; it < 4; ++it) {
        int c = c0 + it * 8 + cl8;
        int w = w0 + wl;
        if (w < 48) tile[it * 8 + cl8][wl] = xp[(size_t)c * 2304 + w] + pe[t * 256 + c];
    }
    __syncthreads();
    int cl = tid & 31, wl8 = tid >> 5;
#pragma unroll
    for (int it = 0; it < 4; ++it) {
        int w = w0 + it * 8 + wl8;
        int c = c0 + cl;
        if (w < 48) {
            size_t n = (size_t)(b * 48 + y) * 48 + w;
            float val = tile[cl][it * 8 + wl8];
            size_t off = (n * 8 + t) * 256 + c;
            h[off] = val;
            hb[off] = f2bf(val);
        }
    }
}

__global__ __launch_bounds__(256) void transpose_out(const float* __restrict__ h,
                                                     float* __restrict__ out) {
    int by = blockIdx.x; int y = by % 48, b = by / 48;
    int c0 = blockIdx.y * 32, w0 = blockIdx.z * 32;
    __shared__ float tile[32][33];
    int tid = threadIdx.x;
    int cl = tid & 31, wl8 = tid >> 5;
#pragma unroll
    for (int it = 0; it < 4; ++it) {
        int w = w0 + it * 8 + wl8;
        if (w < 48) {
            size_t n = (size_t)(b * 48 + y) * 48 + w;
            tile[it * 8 + wl8][cl] = h[n * 2048 + 1792 + c0 + cl];
        }
    }
    __syncthreads();
    int wl = tid & 31, cl8 = tid >> 5;
#pragma unroll
    for (int it = 0; it < 4; ++it) {
        int c = c0 + it * 8 + cl8;
        int w = w0 + wl;
        if (w < 48)
            out[((size_t)(b * 256 + c) * 48 + y) * 48 + w] = tile[wl][it * 8 + cl8];
    }
}

// ---------------------------------------------------------------------------
// bf16 MFMA GEMM, C bf16 = A @ W^T + bias (opt GELU).
// 128x128 tile, BK=64, dbuf 2-phase (counted vmcnt(8), raw s_barrier),
// XOR-swizzled LDS, XCD-swizzled grid, LDS-staged vectorized C store.
template <int ACT>
__global__ __launch_bounds__(256) void mgemm(const unsigned short* __restrict__ A,
                                             const unsigned short* __restrict__ W,
                                             const float* __restrict__ bias,
                                             unsigned short* __restrict__ C,
                                             int M, int N, int K) {
    __shared__ char smem[65536];          // A dbuf 2x16K | B dbuf 2x16K; epi reuse
    const int tid = threadIdx.x;
    // bijective XCD swizzle (all launches have nwg % 8 == 0)
    int nwg = gridDim.x * gridDim.y;
    int orig = blockIdx.y * gridDim.x + blockIdx.x;
    int wg = (orig & 7) * (nwg >> 3) + (orig >> 3);
    int bx = wg % gridDim.x, by = wg / gridDim.x;
    const int m0 = by * 128, n0 = bx * 128;
    const int lane = tid & 63, wv = tid >> 6;
    const int wr = wv >> 1, wc = wv & 1;
    const int lr = lane & 15, lk = lane >> 4;

    f32x4 acc[4][4] = {};

    int so[4], srow[4], sseg[4];
#pragma unroll
    for (int it = 0; it < 4; ++it) {
        int o = it * 4096 + tid * 16;
        so[it] = o;
        srow[it] = o >> 7;
        sseg[it] = ((o >> 4) & 7) ^ (srow[it] & 7);
    }

    const int nt = K >> 6;
    // prologue: stage tile 0 -> buf 0
#pragma unroll
    for (int it = 0; it < 4; ++it)
        GLD_LDS16(W + (size_t)(n0 + srow[it]) * K + sseg[it] * 8, smem + 32768 + so[it]);
#pragma unroll
    for (int it = 0; it < 4; ++it)
        GLD_LDS16(A + (size_t)(m0 + srow[it]) * K + sseg[it] * 8, smem + so[it]);

    for (int t = 0; t < nt; ++t) {
        const int cur = t & 1;
        char* Ac = smem + cur * 16384;
        char* Bc = smem + 32768 + cur * 16384;
        if (t + 1 < nt) {
            const int k1 = (t + 1) << 6;
            char* An = smem + (cur ^ 1) * 16384;
            char* Bn = smem + 32768 + (cur ^ 1) * 16384;
#pragma unroll
            for (int it = 0; it < 4; ++it)
                GLD_LDS16(W + (size_t)(n0 + srow[it]) * K + k1 + sseg[it] * 8, Bn + so[it]);
#pragma unroll
            for (int it = 0; it < 4; ++it)
                GLD_LDS16(A + (size_t)(m0 + srow[it]) * K + k1 + sseg[it] * 8, An + so[it]);
            asm volatile("s_waitcnt vmcnt(8)" ::: "memory");   // tile t done; t+1 in flight
        } else {
            asm volatile("s_waitcnt vmcnt(0)" ::: "memory");
        }
        __builtin_amdgcn_s_barrier();
#pragma unroll
        for (int kc = 0; kc < 2; ++kc) {
            bf16x8 fA[4], fB[4];
            int slot = kc * 4 + lk;
#pragma unroll
            for (int f = 0; f < 4; ++f) {
                int row = wr * 64 + f * 16 + lr;
                fA[f] = *(const bf16x8*)(Ac + row * 128 + ((slot ^ (row & 7)) << 4));
                int col = wc * 64 + f * 16 + lr;
                fB[f] = *(const bf16x8*)(Bc + col * 128 + ((slot ^ (col & 7)) << 4));
            }
#pragma unroll
            for (int fi = 0; fi < 4; ++fi)
#pragma unroll
                for (int fj = 0; fj < 4; ++fj)
                    acc[fi][fj] = __builtin_amdgcn_mfma_f32_16x16x32_bf16(
                        fA[fi], fB[fj], acc[fi][fj], 0, 0, 0);
        }
        __builtin_amdgcn_s_barrier();
    }

    // epilogue: bias(+GELU) -> LDS [128][144] bf16 -> vectorized 16B stores
    unsigned short* S = (unsigned short*)smem;
#pragma unroll
    for (int fi = 0; fi < 4; ++fi) {
        int rl = wr * 64 + fi * 16 + lk * 4;
#pragma unroll
        for (int fj = 0; fj < 4; ++fj) {
            int cl = wc * 64 + fj * 16 + lr;
            float bv = bias[n0 + cl];
#pragma unroll
            for (int r = 0; r < 4; ++r) {
                float v = acc[fi][fj][r] + bv;
                if (ACT) v = 0.5f * v * (1.0f + erff(v * 0.70710678118654752f));
                S[(rl + r) * 144 + cl] = f2bf(v);
            }
        }
    }
    __syncthreads();
#pragma unroll
    for (int it = 0; it < 8; ++it) {
        int idx = it * 256 + tid;
        int row = idx >> 4, c8 = (idx & 15) * 8;
        bf16x8 v = *(const bf16x8*)&S[row * 144 + c8];
        *(bf16x8*)&C[(size_t)(m0 + row) * N + n0 + c8] = v;
    }
}

// ---------------------------------------------------------------------------
// Fused GEMM + residual + LayerNorm (v2):
//   z = h + (A @ W^T + bias);  h = (z-mean)/sqrt(var+eps)*g + be;  hb = bf16(h)
// 64-row x 256-col tile, 4 waves x (16 rows x 256 cols).
// OPERAND-SWAP: mfma(fW, fH) so each lane holds 4 CONSECUTIVE out-cols of one
// h-row (row = lane&15, col = fj*16 + lk*4 + r) -> float4-coalesced residual
// read, h store, hb store; LN stats reduce over lanes {lr,lr+16,lr+32,lr+48}.
__global__ __launch_bounds__(256) void mgemm_ln(const unsigned short* __restrict__ A,
                                                const unsigned short* __restrict__ W,
                                                const float* __restrict__ bias,
                                                float* __restrict__ h,
                                                unsigned short* __restrict__ hb,
                                                const float* __restrict__ g,
                                                const float* __restrict__ be,
                                                int M, int K) {
    __shared__ char smem[40960];          // Hs[64][64] 8K | Ws[256][64] 32K
    const int tid = threadIdx.x;
    int nwg = gridDim.x;
    int orig = blockIdx.x;
    int wg = (orig & 7) * (nwg >> 3) + (orig >> 3);   // bijective (nwg%8==0)
    const int m0 = wg * 64;
    const int lane = tid & 63, wv = tid >> 6;
    const int lr = lane & 15, lk = lane >> 4;
    char* Hs = smem;
    char* Ws = smem + 8192;

    f32x4 acc[16] = {};

    int soA[2], srA[2], ssA[2];
#pragma unroll
    for (int it = 0; it < 2; ++it) {
        int o = it * 4096 + tid * 16;
        soA[it] = o; srA[it] = o >> 7;
        ssA[it] = ((o >> 4) & 7) ^ (srA[it] & 7);
    }
    int soB[8], srB[8], ssB[8];
#pragma unroll
    for (int it = 0; it < 8; ++it) {
        int o = it * 4096 + tid * 16;
        soB[it] = o; srB[it] = o >> 7;
        ssB[it] = ((o >> 4) & 7) ^ (srB[it] & 7);
    }

    for (int k0 = 0; k0 < K; k0 += 64) {
#pragma unroll
        for (int it = 0; it < 8; ++it)
            GLD_LDS16(W + (size_t)srB[it] * K + k0 + ssB[it] * 8, Ws + soB[it]);
#pragma unroll
        for (int it = 0; it < 2; ++it)
            GLD_LDS16(A + (size_t)(m0 + srA[it]) * K + k0 + ssA[it] * 8, Hs + soA[it]);
        asm volatile("s_waitcnt vmcnt(0)" ::: "memory");
        __builtin_amdgcn_s_barrier();
#pragma unroll
        for (int kc = 0; kc < 2; ++kc) {
            int slot = kc * 4 + lk;
            int hrow = wv * 16 + lr;
            bf16x8 fH = *(const bf16x8*)(Hs + hrow * 128 + ((slot ^ (hrow & 7)) << 4));
#pragma unroll
            for (int fj = 0; fj < 16; ++fj) {
                int col = fj * 16 + lr;
                bf16x8 fW = *(const bf16x8*)(Ws + col * 128 + ((slot ^ (col & 7)) << 4));
                acc[fj] = __builtin_amdgcn_mfma_f32_16x16x32_bf16(fW, fH, acc[fj], 0, 0, 0);
            }
        }
        __builtin_amdgcn_s_barrier();
    }

    // ---- residual add (coalesced float4) + per-lane partial stats ----
    const int row = m0 + wv * 16 + lr;
    float s = 0.f, sq = 0.f;
#pragma unroll
    for (int fj = 0; fj < 16; ++fj) {
        int c0 = fj * 16 + lk * 4;
        float4 hv = *(const float4*)&h[(size_t)row * 256 + c0];
        float4 bv = *(const float4*)&bias[c0];
        float* hp = &hv.x; float* bp = &bv.x;
#pragma unroll
        for (int r = 0; r < 4; ++r) {
            float z = acc[fj][r] + bp[r] + hp[r];
            acc[fj][r] = z;
            s += z; sq += z * z;
        }
    }
    // row stats: reduce over lanes sharing lr (lk = 0..3)
    s  += __shfl_xor(s, 16);  s  += __shfl_xor(s, 32);
    sq += __shfl_xor(sq, 16); sq += __shfl_xor(sq, 32);
    float mean = s * (1.f / 256.f);
    float var  = sq * (1.f / 256.f) - mean * mean;
    float inv  = 1.0f / sqrtf(var + 1e-5f);
    // ---- normalize + coalesced stores ----
#pragma unroll
    for (int fj = 0; fj < 16; ++fj) {
        int c0 = fj * 16 + lk * 4;
        float4 gv = *(const float4*)&g[c0];
        float4 bev = *(const float4*)&be[c0];
        float* gp = &gv.x; float* bp = &bev.x;
        float4 o; float* op = &o.x;
        bf16x4 ob;
#pragma unroll
        for (int r = 0; r < 4; ++r) {
            float z = (acc[fj][r] - mean) * inv * gp[r] + bp[r];
            op[r] = z;
            ob[r] = (short)f2bf(z);
        }
        size_t off = (size_t)row * 256 + c0;
        *(float4*)&h[off] = o;
        *(bf16x4*)&hb[off] = ob;
    }
}

// ---------------------------------------------------------------------------
// Causal MHSA: qkv packed bf16 [row][768] (q|k|v), ctx out bf16 [row][256].
__global__ __launch_bounds__(256) void attn_kernel(const unsigned short* __restrict__ qkv,
                                                   unsigned short* __restrict__ ctx) {
    __shared__ float Qs[8 * 260], Ks[8 * 260], Vs[8 * 260];
    int n = blockIdx.x;
    int tid = threadIdx.x;
    size_t base = (size_t)n * 6144;             // 8*768
#pragma unroll
    for (int it = 0; it < 6; ++it) {
        int i4 = it * 256 + tid;                // 0..1535
        int t = i4 / 192;
        int c4 = (i4 - t * 192) * 4;            // 0..764, mult of 4
        const unsigned short* p = qkv + base + (size_t)t * 768 + c4;
        float4 f = {bf2f(p[0]), bf2f(p[1]), bf2f(p[2]), bf2f(p[3])};
        float* dst = (c4 < 256) ? &Qs[t * 260 + c4]
                   : (c4 < 512) ? &Ks[t * 260 + (c4 - 256)]
                                : &Vs[t * 260 + (c4 - 512)];
        *(float4*)dst = f;
    }
    __syncthreads();
    int wid = tid >> 6, lane = tid & 63;
    int t = lane >> 3, s = lane & 7;
    size_t obase = (size_t)n * 2048;
    for (int hh = wid; hh < 8; hh += 4) {
        float acc = 0.f;
        int qb = t * 260 + hh * 32, kb = s * 260 + hh * 32;
#pragma unroll
        for (int jj = 0; jj < 8; ++jj) {
            float4 qv = *(const float4*)&Qs[qb + jj * 4];
            float4 kv = *(const float4*)&Ks[kb + jj * 4];
            acc += qv.x * kv.x + qv.y * kv.y + qv.z * kv.z + qv.w * kv.w;
        }
        acc *= 0.17677669529663687f;            // 1/sqrt(32)
        if (s > t) acc = -1e30f;
        float m = acc;
        m = fmaxf(m, __shfl_xor(m, 1));
        m = fmaxf(m, __shfl_xor(m, 2));
        m = fmaxf(m, __shfl_xor(m, 4));
        float e = __expf(acc - m);
        float sum = e;
        sum += __shfl_xor(sum, 1);
        sum += __shfl_xor(sum, 2);
        sum += __shfl_xor(sum, 4);
        float p = e / sum;
        float a4[4] = {0.f, 0.f, 0.f, 0.f};
#pragma unroll
        for (int s2 = 0; s2 < 8; ++s2) {
            float ps = __shfl(p, (lane & ~7) | s2);
            int vb = s2 * 260 + hh * 32 + s;
#pragma unroll
            for (int r = 0; r < 4; ++r) a4[r] += ps * Vs[vb + 8 * r];
        }
#pragma unroll
        for (int r = 0; r < 4; ++r)
            ctx[obase + t * 256 + hh * 32 + s + 8 * r] = f2bf(a4[r]);
    }
}

// ---------------------------------------------------------------------------
extern "C" void kernel_launch(void* const* d_in, const int* in_sizes, int n_in,
                              void* d_out, int out_size, void* d_ws, size_t ws_size,
                              hipStream_t stream) {
    const float* x   = (const float*)d_in[0];
    const float* Wq  = (const float*)d_in[1];
    const float* bq  = (const float*)d_in[2];
    const float* Wk  = (const float*)d_in[3];
    const float* bk  = (const float*)d_in[4];
    const float* Wv  = (const float*)d_in[5];
    const float* bv  = (const float*)d_in[6];
    const float* Wo  = (const float*)d_in[7];
    const float* bo  = (const float*)d_in[8];
    const float* g1  = (const float*)d_in[9];
    const float* be1 = (const float*)d_in[10];
    const float* W1  = (const float*)d_in[11];
    const float* b1  = (const float*)d_in[12];
    const float* W2  = (const float*)d_in[13];
    const float* b2  = (const float*)d_in[14];
    const float* g2  = (const float*)d_in[15];
    const float* be2 = (const float*)d_in[16];

    // ---- workspace layout (bytes) ----
    // nch=1 end = 305,160,192; nch=2 end = 210,788,352 (ws proven >= 264.3 MB)
    char* base = (char*)d_ws;
    const size_t O_PE = 0;                          // 16 KB reserved
    const size_t O_W  = 16384;                      // bf16 weights (2 layers)
    const size_t O_BQ = O_W + 2 * 1572864ull;       // packed qkv bias
    const size_t O_H  = O_BQ + 8192;                // h fp32
    const size_t O_HB = O_H + (size_t)TOK * 1024;   // hb bf16
    const size_t O_P1 = O_HB + (size_t)TOK * 512;   // qkv / f1 out pool
    const int nch = (ws_size >= 305160192ull) ? 1 : 2;
    const int Mc = TOK / nch;
    const size_t O_P2 = O_P1 + (size_t)Mc * 2048;   // ctx bf16

    float*          pe   = (float*)(base + O_PE);
    unsigned short* wB   = (unsigned short*)(base + O_W);
    float*          bqkv = (float*)(base + O_BQ);
    float*          h    = (float*)(base + O_H);
    unsigned short* hb   = (unsigned short*)(base + O_HB);
    unsigned short* p1   = (unsigned short*)(base + O_P1);
    unsigned short* ctxb = (unsigned short*)(base + O_P2);

    for (int l = 0; l < 2; ++l) {
        unsigned short* wl = wB + (size_t)l * 786432;
        convertw<<<64,  256, 0, stream>>>(Wq + (size_t)l * 65536,  wl,          16384);
        convertw<<<64,  256, 0, stream>>>(Wk + (size_t)l * 65536,  wl + 65536,  16384);
        convertw<<<64,  256, 0, stream>>>(Wv + (size_t)l * 65536,  wl + 131072, 16384);
        convertw<<<64,  256, 0, stream>>>(Wo + (size_t)l * 65536,  wl + 196608, 16384);
        convertw<<<256, 256, 0, stream>>>(W1 + (size_t)l * 262144, wl + 262144, 65536);
        convertw<<<256, 256, 0, stream>>>(W2 + (size_t)l * 262144, wl + 524288, 65536);
    }
    pack_bias<<<2, 768, 0, stream>>>(bq, bk, bv, bqkv);

    pe_fill<<<8, 256, 0, stream>>>(pe);
    transpose_in<<<dim3(1536, 8, 2), 256, 0, stream>>>(x, pe, h, hb);

    const int gy = Mc / 128;
    for (int l = 0; l < 2; ++l) {
        unsigned short* wqkv = wB + (size_t)l * 786432;
        unsigned short* wo   = wqkv + 196608;
        unsigned short* w1   = wqkv + 262144;
        unsigned short* w2   = wqkv + 524288;

        for (int chn = 0; chn < nch; ++chn) {
            size_t moff = (size_t)chn * Mc;
            unsigned short* hbc = hb + moff * 256;
            float*          hc  = h  + moff * 256;
            // fused qkv projection (N=768)
            mgemm<0><<<dim3(6, gy), 256, 0, stream>>>(hbc, wqkv, bqkv + l * 768, p1, Mc, 768, 256);
            attn_kernel<<<Mc / 8, 256, 0, stream>>>(p1, ctxb);
            // Wo projection + residual + LN1 (updates h, hb)
            mgemm_ln<<<Mc / 64, 256, 0, stream>>>(ctxb, wo, bo + l * 256, hc, hbc,
                                                  g1 + l * 256, be1 + l * 256, Mc, 256);
            // FFN up + GELU
            mgemm<1><<<dim3(8, gy), 256, 0, stream>>>(hbc, w1, b1 + l * 1024, p1, Mc, 1024, 256);
            // FFN down + residual + LN2
            mgemm_ln<<<Mc / 64, 256, 0, stream>>>(p1, w2, b2 + l * 256, hc, hbc,
                                                  g2 + l * 256, be2 + l * 256, Mc, 1024);
        }
    }

    transpose_out<<<dim3(192, 8, 2), 256, 0, stream>>>(h, (float*)d_out);
}

// Round 7
// 967.033 us; speedup vs baseline: 1.0494x; 1.0494x over previous
//
#include <hip/hip_runtime.h>
#include <math.h>

// Problem constants: B=4, T=8, C=d=256, H=W=48, L=2, nh=8, dk=32
#define SEQ   9216          // B*H*W
#define TOK   73728         // SEQ*T

typedef short bf16x8 __attribute__((ext_vector_type(8)));
typedef short bf16x4 __attribute__((ext_vector_type(4)));
typedef float f32x4  __attribute__((ext_vector_type(4)));

#define GLD_LDS16(gsrc, ldst)                                                      \
    __builtin_amdgcn_global_load_lds(                                              \
        (const __attribute__((address_space(1))) unsigned int*)(gsrc),             \
        (__attribute__((address_space(3))) unsigned int*)(ldst), 16, 0, 0)

__device__ __forceinline__ unsigned short f2bf(float f) {
    unsigned u = __builtin_bit_cast(unsigned, f);
    unsigned r = (u + 0x7fffu + ((u >> 16) & 1u)) >> 16;
    return (unsigned short)r;
}
__device__ __forceinline__ float bf2f(unsigned short h) {
    return __builtin_bit_cast(float, (unsigned)h << 16);
}

// ---------------------------------------------------------------------------
__global__ void pe_fill(float* __restrict__ pe) {
    int idx = blockIdx.x * 256 + threadIdx.x;   // 0..2047
    int t = idx >> 8, c = idx & 255;
    int i2 = c & ~1;
    float div = __expf((float)i2 * (-logf(10000.f) / 256.f));
    float ang = (float)t * div;
    pe[idx] = (c & 1) ? cosf(ang) : sinf(ang);
}

__global__ void convertw(const float* __restrict__ src, unsigned short* __restrict__ dst, int n4) {
    int i = blockIdx.x * 256 + threadIdx.x;
    if (i < n4) {
        float4 v = *(const float4*)(src + (size_t)i * 4);
        unsigned short* o = dst + (size_t)i * 4;
        o[0] = f2bf(v.x); o[1] = f2bf(v.y); o[2] = f2bf(v.z); o[3] = f2bf(v.w);
    }
}

__global__ void pack_bias(const float* __restrict__ bq, const float* __restrict__ bk,
                          const float* __restrict__ bv, float* __restrict__ dst) {
    int l = blockIdx.x, i = threadIdx.x;        // block = 768 threads
    float v = (i < 256) ? bq[l * 256 + i] : (i < 512) ? bk[l * 256 + i - 256]
                                                      : bv[l * 256 + i - 512];
    dst[l * 768 + i] = v;
}

// ---------------------------------------------------------------------------
// x (B,T,C,H,W) -> h (n, t, c) fp32 AND hb bf16, with += pe[t,c].
__global__ __launch_bounds__(256) void transpose_in(const float* __restrict__ x,
                                                    const float* __restrict__ pe,
                                                    float* __restrict__ h,
                                                    unsigned short* __restrict__ hb) {
    int bty = blockIdx.x;
    int y = bty % 48; int bt = bty / 48; int t = bt & 7; int b = bt >> 3;
    int c0 = blockIdx.y * 32, w0 = blockIdx.z * 32;
    __shared__ float tile[32][33];
    int tid = threadIdx.x;
    const float* xp = x + ((size_t)(b * 8 + t) * 256) * 2304 + (size_t)y * 48;
    int wl = tid & 31, cl8 = tid >> 5;
#pragma unroll
    for (int it = 0; it < 4; ++it) {
        int c = c0 + it * 8 + cl8;
        int w = w0 + wl;
        if (w < 48) tile[it * 8 + cl8][wl] = xp[(size_t)c * 2304 + w] + pe[t * 256 + c];
    }
    __syncthreads();
    int cl = tid & 31, wl8 = tid >> 5;
#pragma unroll
    for (int it = 0; it < 4; ++it) {
        int w = w0 + it * 8 + wl8;
        int c = c0 + cl;
        if (w < 48) {
            size_t n = (size_t)(b * 48 + y) * 48 + w;
            float val = tile[cl][it * 8 + wl8];
            size_t off = (n * 8 + t) * 256 + c;
            h[off] = val;
            hb[off] = f2bf(val);
        }
    }
}

__global__ __launch_bounds__(256) void transpose_out(const float* __restrict__ h,
                                                     float* __restrict__ out) {
    int by = blockIdx.x; int y = by % 48, b = by / 48;
    int c0 = blockIdx.y * 32, w0 = blockIdx.z * 32;
    __shared__ float tile[32][33];
    int tid = threadIdx.x;
    int cl = tid & 31, wl8 = tid >> 5;
#pragma unroll
    for (int it = 0; it < 4; ++it) {
        int w = w0 + it * 8 + wl8;
        if (w < 48) {
            size_t n = (size_t)(b * 48 + y) * 48 + w;
            tile[it * 8 + wl8][cl] = h[n * 2048 + 1792 + c0 + cl];
        }
    }
    __syncthreads();
    int wl = tid & 31, cl8 = tid >> 5;
#pragma unroll
    for (int it = 0; it < 4; ++it) {
        int c = c0 + it * 8 + cl8;
        int w = w0 + wl;
        if (w < 48)
            out[((size_t)(b * 256 + c) * 48 + y) * 48 + w] = tile[wl][it * 8 + cl8];
    }
}

// ---------------------------------------------------------------------------
// bf16 MFMA GEMM, C bf16 = A @ W^T + bias (opt GELU).
// 128x128 tile, BK=64, SINGLE-buffer 1-phase (32 KB loop LDS -> 4 blocks/CU),
// XOR-swizzled LDS, XCD-swizzled grid, LDS-restaged vectorized C store.
template <int ACT>
__global__ __launch_bounds__(256) void mgemm(const unsigned short* __restrict__ A,
                                             const unsigned short* __restrict__ W,
                                             const float* __restrict__ bias,
                                             unsigned short* __restrict__ C,
                                             int M, int N, int K) {
    __shared__ char smem[36864];          // loop: As@0 16K | Bs@16K 16K; epi: [128][144] bf16
    const int tid = threadIdx.x;
    // bijective XCD swizzle (all launches have nwg % 8 == 0)
    int nwg = gridDim.x * gridDim.y;
    int orig = blockIdx.y * gridDim.x + blockIdx.x;
    int wg = (orig & 7) * (nwg >> 3) + (orig >> 3);
    int bx = wg % gridDim.x, by = wg / gridDim.x;
    const int m0 = by * 128, n0 = bx * 128;
    const int lane = tid & 63, wv = tid >> 6;
    const int wr = wv >> 1, wc = wv & 1;
    const int lr = lane & 15, lk = lane >> 4;
    char* As = smem;
    char* Bs = smem + 16384;

    f32x4 acc[4][4] = {};

    int so[4], srow[4], sseg[4];
#pragma unroll
    for (int it = 0; it < 4; ++it) {
        int o = it * 4096 + tid * 16;
        so[it] = o;
        srow[it] = o >> 7;
        sseg[it] = ((o >> 4) & 7) ^ (srow[it] & 7);
    }

    for (int k0 = 0; k0 < K; k0 += 64) {
#pragma unroll
        for (int it = 0; it < 4; ++it)
            GLD_LDS16(W + (size_t)(n0 + srow[it]) * K + k0 + sseg[it] * 8, Bs + so[it]);
#pragma unroll
        for (int it = 0; it < 4; ++it)
            GLD_LDS16(A + (size_t)(m0 + srow[it]) * K + k0 + sseg[it] * 8, As + so[it]);
        asm volatile("s_waitcnt vmcnt(0)" ::: "memory");
        __builtin_amdgcn_s_barrier();
#pragma unroll
        for (int kc = 0; kc < 2; ++kc) {
            bf16x8 fA[4], fB[4];
            int slot = kc * 4 + lk;
#pragma unroll
            for (int f = 0; f < 4; ++f) {
                int row = wr * 64 + f * 16 + lr;
                fA[f] = *(const bf16x8*)(As + row * 128 + ((slot ^ (row & 7)) << 4));
                int col = wc * 64 + f * 16 + lr;
                fB[f] = *(const bf16x8*)(Bs + col * 128 + ((slot ^ (col & 7)) << 4));
            }
#pragma unroll
            for (int fi = 0; fi < 4; ++fi)
#pragma unroll
                for (int fj = 0; fj < 4; ++fj)
                    acc[fi][fj] = __builtin_amdgcn_mfma_f32_16x16x32_bf16(
                        fA[fi], fB[fj], acc[fi][fj], 0, 0, 0);
        }
        __builtin_amdgcn_s_barrier();
    }

    // epilogue: bias(+GELU) -> LDS [128][144] bf16 -> vectorized 16B stores
    unsigned short* S = (unsigned short*)smem;
#pragma unroll
    for (int fi = 0; fi < 4; ++fi) {
        int rl = wr * 64 + fi * 16 + lk * 4;
#pragma unroll
        for (int fj = 0; fj < 4; ++fj) {
            int cl = wc * 64 + fj * 16 + lr;
            float bv = bias[n0 + cl];
#pragma unroll
            for (int r = 0; r < 4; ++r) {
                float v = acc[fi][fj][r] + bv;
                if (ACT) v = 0.5f * v * (1.0f + erff(v * 0.70710678118654752f));
                S[(rl + r) * 144 + cl] = f2bf(v);
            }
        }
    }
    __syncthreads();
#pragma unroll
    for (int it = 0; it < 8; ++it) {
        int idx = it * 256 + tid;
        int row = idx >> 4, c8 = (idx & 15) * 8;
        bf16x8 v = *(const bf16x8*)&S[row * 144 + c8];
        *(bf16x8*)&C[(size_t)(m0 + row) * N + n0 + c8] = v;
    }
}

// ---------------------------------------------------------------------------
// Fused GEMM + residual + LayerNorm (v3 — occupancy-first):
//   z = h + (A @ W^T + bias);  h = (z-mean)/sqrt(var+eps)*g + be;  hb = bf16(h)
// 32-row x 256-col tile, 128 threads (2 waves x 16 rows x 256 cols).
// Grid = Mc/32 (1152 at nch=2, 4.5 blocks/CU); LDS 36 KB -> 4 blocks/CU.
// OPERAND-SWAP mfma(fW, fH): lane holds row = lane&15 (+wv*16), 4 consecutive
// out-cols (fj*16 + lk*4 + r) -> float4-coalesced residual read/stores;
// LN stats reduce over lk via 2 shfl_xor.
__global__ __launch_bounds__(128) void mgemm_ln(const unsigned short* __restrict__ A,
                                                const unsigned short* __restrict__ W,
                                                const float* __restrict__ bias,
                                                float* __restrict__ h,
                                                unsigned short* __restrict__ hb,
                                                const float* __restrict__ g,
                                                const float* __restrict__ be,
                                                int M, int K) {
    __shared__ char smem[36864];          // Hs[32][64] 4K @0 | Ws[256][64] 32K @4096
    const int tid = threadIdx.x;
    int nwg = gridDim.x;
    int orig = blockIdx.x;
    int wg = (orig & 7) * (nwg >> 3) + (orig >> 3);   // bijective (nwg%8==0)
    const int m0 = wg * 32;
    const int lane = tid & 63, wv = tid >> 6;          // wv in {0,1}
    const int lr = lane & 15, lk = lane >> 4;
    char* Hs = smem;
    char* Ws = smem + 4096;

    f32x4 acc[16] = {};

    for (int k0 = 0; k0 < K; k0 += 64) {
        // W staging: 32 KB -> 16 x GLD16 per thread (128 thr)
#pragma unroll
        for (int it = 0; it < 16; ++it) {
            int o = it * 2048 + tid * 16;
            int r = o >> 7;                           // W row (out-col) 0..255
            int sg = ((o >> 4) & 7) ^ (r & 7);        // pre-swizzled source slot
            GLD_LDS16(W + (size_t)r * K + k0 + sg * 8, Ws + o);
        }
        // H staging: 4 KB -> 2 x GLD16 per thread
#pragma unroll
        for (int it = 0; it < 2; ++it) {
            int o = it * 2048 + tid * 16;
            int r = o >> 7;                           // h row 0..31
            int sg = ((o >> 4) & 7) ^ (r & 7);
            GLD_LDS16(A + (size_t)(m0 + r) * K + k0 + sg * 8, Hs + o);
        }
        asm volatile("s_waitcnt vmcnt(0)" ::: "memory");
        __builtin_amdgcn_s_barrier();
#pragma unroll
        for (int kc = 0; kc < 2; ++kc) {
            int slot = kc * 4 + lk;
            int hrow = wv * 16 + lr;
            bf16x8 fH = *(const bf16x8*)(Hs + hrow * 128 + ((slot ^ (hrow & 7)) << 4));
#pragma unroll
            for (int fj = 0; fj < 16; ++fj) {
                int col = fj * 16 + lr;
                bf16x8 fW = *(const bf16x8*)(Ws + col * 128 + ((slot ^ (col & 7)) << 4));
                acc[fj] = __builtin_amdgcn_mfma_f32_16x16x32_bf16(fW, fH, acc[fj], 0, 0, 0);
            }
        }
        __builtin_amdgcn_s_barrier();
    }

    // ---- residual add (coalesced float4) + per-lane partial stats ----
    const int row = m0 + wv * 16 + lr;
    float s = 0.f, sq = 0.f;
#pragma unroll
    for (int fj = 0; fj < 16; ++fj) {
        int c0 = fj * 16 + lk * 4;
        float4 hv = *(const float4*)&h[(size_t)row * 256 + c0];
        float4 bv = *(const float4*)&bias[c0];
        float* hp = &hv.x; float* bp = &bv.x;
#pragma unroll
        for (int r = 0; r < 4; ++r) {
            float z = acc[fj][r] + bp[r] + hp[r];
            acc[fj][r] = z;
            s += z; sq += z * z;
        }
    }
    // row stats: reduce over lanes sharing lr (lk = 0..3)
    s  += __shfl_xor(s, 16);  s  += __shfl_xor(s, 32);
    sq += __shfl_xor(sq, 16); sq += __shfl_xor(sq, 32);
    float mean = s * (1.f / 256.f);
    float var  = sq * (1.f / 256.f) - mean * mean;
    float inv  = 1.0f / sqrtf(var + 1e-5f);
    // ---- normalize + coalesced stores ----
#pragma unroll
    for (int fj = 0; fj < 16; ++fj) {
        int c0 = fj * 16 + lk * 4;
        float4 gv = *(const float4*)&g[c0];
        float4 bev = *(const float4*)&be[c0];
        float* gp = &gv.x; float* bp = &bev.x;
        float4 o; float* op = &o.x;
        bf16x4 ob;
#pragma unroll
        for (int r = 0; r < 4; ++r) {
            float z = (acc[fj][r] - mean) * inv * gp[r] + bp[r];
            op[r] = z;
            ob[r] = (short)f2bf(z);
        }
        size_t off = (size_t)row * 256 + c0;
        *(float4*)&h[off] = o;
        *(bf16x4*)&hb[off] = ob;
    }
}

// ---------------------------------------------------------------------------
// Causal MHSA: qkv packed bf16 [row][768] (q|k|v), ctx out bf16 [row][256].
__global__ __launch_bounds__(256) void attn_kernel(const unsigned short* __restrict__ qkv,
                                                   unsigned short* __restrict__ ctx) {
    __shared__ float Qs[8 * 260], Ks[8 * 260], Vs[8 * 260];
    int n = blockIdx.x;
    int tid = threadIdx.x;
    size_t base = (size_t)n * 6144;             // 8*768
#pragma unroll
    for (int it = 0; it < 6; ++it) {
        int i4 = it * 256 + tid;                // 0..1535
        int t = i4 / 192;
        int c4 = (i4 - t * 192) * 4;            // 0..764, mult of 4
        const unsigned short* p = qkv + base + (size_t)t * 768 + c4;
        float4 f = {bf2f(p[0]), bf2f(p[1]), bf2f(p[2]), bf2f(p[3])};
        float* dst = (c4 < 256) ? &Qs[t * 260 + c4]
                   : (c4 < 512) ? &Ks[t * 260 + (c4 - 256)]
                                : &Vs[t * 260 + (c4 - 512)];
        *(float4*)dst = f;
    }
    __syncthreads();
    int wid = tid >> 6, lane = tid & 63;
    int t = lane >> 3, s = lane & 7;
    size_t obase = (size_t)n * 2048;
    for (int hh = wid; hh < 8; hh += 4) {
        float acc = 0.f;
        int qb = t * 260 + hh * 32, kb = s * 260 + hh * 32;
#pragma unroll
        for (int jj = 0; jj < 8; ++jj) {
            float4 qv = *(const float4*)&Qs[qb + jj * 4];
            float4 kv = *(const float4*)&Ks[kb + jj * 4];
            acc += qv.x * kv.x + qv.y * kv.y + qv.z * kv.z + qv.w * kv.w;
        }
        acc *= 0.17677669529663687f;            // 1/sqrt(32)
        if (s > t) acc = -1e30f;
        float m = acc;
        m = fmaxf(m, __shfl_xor(m, 1));
        m = fmaxf(m, __shfl_xor(m, 2));
        m = fmaxf(m, __shfl_xor(m, 4));
        float e = __expf(acc - m);
        float sum = e;
        sum += __shfl_xor(sum, 1);
        sum += __shfl_xor(sum, 2);
        sum += __shfl_xor(sum, 4);
        float p = e / sum;
        float a4[4] = {0.f, 0.f, 0.f, 0.f};
#pragma unroll
        for (int s2 = 0; s2 < 8; ++s2) {
            float ps = __shfl(p, (lane & ~7) | s2);
            int vb = s2 * 260 + hh * 32 + s;
#pragma unroll
            for (int r = 0; r < 4; ++r) a4[r] += ps * Vs[vb + 8 * r];
        }
#pragma unroll
        for (int r = 0; r < 4; ++r)
            ctx[obase + t * 256 + hh * 32 + s + 8 * r] = f2bf(a4[r]);
    }
}

// ---------------------------------------------------------------------------
extern "C" void kernel_launch(void* const* d_in, const int* in_sizes, int n_in,
                              void* d_out, int out_size, void* d_ws, size_t ws_size,
                              hipStream_t stream) {
    const float* x   = (const float*)d_in[0];
    const float* Wq  = (const float*)d_in[1];
    const float* bq  = (const float*)d_in[2];
    const float* Wk  = (const float*)d_in[3];
    const float* bk  = (const float*)d_in[4];
    const float* Wv  = (const float*)d_in[5];
    const float* bv  = (const float*)d_in[6];
    const float* Wo  = (const float*)d_in[7];
    const float* bo  = (const float*)d_in[8];
    const float* g1  = (const float*)d_in[9];
    const float* be1 = (const float*)d_in[10];
    const float* W1  = (const float*)d_in[11];
    const float* b1  = (const float*)d_in[12];
    const float* W2  = (const float*)d_in[13];
    const float* b2  = (const float*)d_in[14];
    const float* g2  = (const float*)d_in[15];
    const float* be2 = (const float*)d_in[16];

    // ---- workspace layout (bytes) ----
    // nch=1 end = 305,160,192; nch=2 end = 210,788,352 (ws proven >= 264.3 MB)
    char* base = (char*)d_ws;
    const size_t O_PE = 0;                          // 16 KB reserved
    const size_t O_W  = 16384;                      // bf16 weights (2 layers)
    const size_t O_BQ = O_W + 2 * 1572864ull;       // packed qkv bias
    const size_t O_H  = O_BQ + 8192;                // h fp32
    const size_t O_HB = O_H + (size_t)TOK * 1024;   // hb bf16
    const size_t O_P1 = O_HB + (size_t)TOK * 512;   // qkv / f1 out pool
    const int nch = (ws_size >= 305160192ull) ? 1 : 2;
    const int Mc = TOK / nch;
    const size_t O_P2 = O_P1 + (size_t)Mc * 2048;   // ctx bf16

    float*          pe   = (float*)(base + O_PE);
    unsigned short* wB   = (unsigned short*)(base + O_W);
    float*          bqkv = (float*)(base + O_BQ);
    float*          h    = (float*)(base + O_H);
    unsigned short* hb   = (unsigned short*)(base + O_HB);
    unsigned short* p1   = (unsigned short*)(base + O_P1);
    unsigned short* ctxb = (unsigned short*)(base + O_P2);

    for (int l = 0; l < 2; ++l) {
        unsigned short* wl = wB + (size_t)l * 786432;
        convertw<<<64,  256, 0, stream>>>(Wq + (size_t)l * 65536,  wl,          16384);
        convertw<<<64,  256, 0, stream>>>(Wk + (size_t)l * 65536,  wl + 65536,  16384);
        convertw<<<64,  256, 0, stream>>>(Wv + (size_t)l * 65536,  wl + 131072, 16384);
        convertw<<<64,  256, 0, stream>>>(Wo + (size_t)l * 65536,  wl + 196608, 16384);
        convertw<<<256, 256, 0, stream>>>(W1 + (size_t)l * 262144, wl + 262144, 65536);
        convertw<<<256, 256, 0, stream>>>(W2 + (size_t)l * 262144, wl + 524288, 65536);
    }
    pack_bias<<<2, 768, 0, stream>>>(bq, bk, bv, bqkv);

    pe_fill<<<8, 256, 0, stream>>>(pe);
    transpose_in<<<dim3(1536, 8, 2), 256, 0, stream>>>(x, pe, h, hb);

    const int gy = Mc / 128;
    for (int l = 0; l < 2; ++l) {
        unsigned short* wqkv = wB + (size_t)l * 786432;
        unsigned short* wo   = wqkv + 196608;
        unsigned short* w1   = wqkv + 262144;
        unsigned short* w2   = wqkv + 524288;

        for (int chn = 0; chn < nch; ++chn) {
            size_t moff = (size_t)chn * Mc;
            unsigned short* hbc = hb + moff * 256;
            float*          hc  = h  + moff * 256;
            // fused qkv projection (N=768)
            mgemm<0><<<dim3(6, gy), 256, 0, stream>>>(hbc, wqkv, bqkv + l * 768, p1, Mc, 768, 256);
            attn_kernel<<<Mc / 8, 256, 0, stream>>>(p1, ctxb);
            // Wo projection + residual + LN1 (updates h, hb)
            mgemm_ln<<<Mc / 32, 128, 0, stream>>>(ctxb, wo, bo + l * 256, hc, hbc,
                                                  g1 + l * 256, be1 + l * 256, Mc, 256);
            // FFN up + GELU
            mgemm<1><<<dim3(8, gy), 256, 0, stream>>>(hbc, w1, b1 + l * 1024, p1, Mc, 1024, 256);
            // FFN down + residual + LN2
            mgemm_ln<<<Mc / 32, 128, 0, stream>>>(p1, w2, b2 + l * 256, hc, hbc,
                                                  g2 + l * 256, be2 + l * 256, Mc, 1024);
        }
    }

    transpose_out<<<dim3(192, 8, 2), 256, 0, stream>>>(h, (float*)d_out);
}

// Round 9
// 855.672 us; speedup vs baseline: 1.1860x; 1.1301x over previous
//
#include <hip/hip_runtime.h>
#include <math.h>

// Problem constants: B=4, T=8, C=d=256, H=W=48, L=2, nh=8, dk=32
#define SEQ   9216          // B*H*W
#define TOK   73728         // SEQ*T

typedef short bf16x8 __attribute__((ext_vector_type(8)));
typedef short bf16x4 __attribute__((ext_vector_type(4)));
typedef float f32x4  __attribute__((ext_vector_type(4)));

#define GLD_LDS16(gsrc, ldst)                                                      \
    __builtin_amdgcn_global_load_lds(                                              \
        (const __attribute__((address_space(1))) unsigned int*)(gsrc),             \
        (__attribute__((address_space(3))) unsigned int*)(ldst), 16, 0, 0)

__device__ __forceinline__ unsigned short f2bf(float f) {
    unsigned u = __builtin_bit_cast(unsigned, f);
    unsigned r = (u + 0x7fffu + ((u >> 16) & 1u)) >> 16;
    return (unsigned short)r;
}
__device__ __forceinline__ float bf2f(unsigned short h) {
    return __builtin_bit_cast(float, (unsigned)h << 16);
}

// ---------------------------------------------------------------------------
__global__ void pe_fill(float* __restrict__ pe) {
    int idx = blockIdx.x * 256 + threadIdx.x;   // 0..2047
    int t = idx >> 8, c = idx & 255;
    int i2 = c & ~1;
    float div = __expf((float)i2 * (-logf(10000.f) / 256.f));
    float ang = (float)t * div;
    pe[idx] = (c & 1) ? cosf(ang) : sinf(ang);
}

__global__ void convertw(const float* __restrict__ src, unsigned short* __restrict__ dst, int n4) {
    int i = blockIdx.x * 256 + threadIdx.x;
    if (i < n4) {
        float4 v = *(const float4*)(src + (size_t)i * 4);
        unsigned short* o = dst + (size_t)i * 4;
        o[0] = f2bf(v.x); o[1] = f2bf(v.y); o[2] = f2bf(v.z); o[3] = f2bf(v.w);
    }
}

__global__ void pack_bias(const float* __restrict__ bq, const float* __restrict__ bk,
                          const float* __restrict__ bv, float* __restrict__ dst) {
    int l = blockIdx.x, i = threadIdx.x;        // block = 768 threads
    float v = (i < 256) ? bq[l * 256 + i] : (i < 512) ? bk[l * 256 + i - 256]
                                                      : bv[l * 256 + i - 512];
    dst[l * 768 + i] = v;
}

// ---------------------------------------------------------------------------
// x (B,T,C,H,W) -> h (n, t, c) fp32 AND hb bf16, with += pe[t,c].
__global__ __launch_bounds__(256) void transpose_in(const float* __restrict__ x,
                                                    const float* __restrict__ pe,
                                                    float* __restrict__ h,
                                                    unsigned short* __restrict__ hb) {
    int bty = blockIdx.x;
    int y = bty % 48; int bt = bty / 48; int t = bt & 7; int b = bt >> 3;
    int c0 = blockIdx.y * 32, w0 = blockIdx.z * 32;
    __shared__ float tile[32][33];
    int tid = threadIdx.x;
    const float* xp = x + ((size_t)(b * 8 + t) * 256) * 2304 + (size_t)y * 48;
    int wl = tid & 31, cl8 = tid >> 5;
#pragma unroll
    for (int it = 0; it < 4; ++it) {
        int c = c0 + it * 8 + cl8;
        int w = w0 + wl;
        if (w < 48) tile[it * 8 + cl8][wl] = xp[(size_t)c * 2304 + w] + pe[t * 256 + c];
    }
    __syncthreads();
    int cl = tid & 31, wl8 = tid >> 5;
#pragma unroll
    for (int it = 0; it < 4; ++it) {
        int w = w0 + it * 8 + wl8;
        int c = c0 + cl;
        if (w < 48) {
            size_t n = (size_t)(b * 48 + y) * 48 + w;
            float val = tile[cl][it * 8 + wl8];
            size_t off = (n * 8 + t) * 256 + c;
            h[off] = val;
            hb[off] = f2bf(val);
        }
    }
}

__global__ __launch_bounds__(256) void transpose_out(const float* __restrict__ h,
                                                     float* __restrict__ out) {
    int by = blockIdx.x; int y = by % 48, b = by / 48;
    int c0 = blockIdx.y * 32, w0 = blockIdx.z * 32;
    __shared__ float tile[32][33];
    int tid = threadIdx.x;
    int cl = tid & 31, wl8 = tid >> 5;
#pragma unroll
    for (int it = 0; it < 4; ++it) {
        int w = w0 + it * 8 + wl8;
        if (w < 48) {
            size_t n = (size_t)(b * 48 + y) * 48 + w;
            tile[it * 8 + wl8][cl] = h[n * 2048 + 1792 + c0 + cl];
        }
    }
    __syncthreads();
    int wl = tid & 31, cl8 = tid >> 5;
#pragma unroll
    for (int it = 0; it < 4; ++it) {
        int c = c0 + it * 8 + cl8;
        int w = w0 + wl;
        if (w < 48)
            out[((size_t)(b * 256 + c) * 48 + y) * 48 + w] = tile[wl][it * 8 + cl8];
    }
}

// ---------------------------------------------------------------------------
// bf16 MFMA GEMM, C bf16 = A @ W^T + bias (opt GELU).
// 128x128 tile, BK=64, single-buffer (32 KB loop LDS -> 4 blocks/CU),
// XOR-swizzled LDS, XCD-swizzled grid, LDS-restaged vectorized C store.
template <int ACT>
__global__ __launch_bounds__(256) void mgemm(const unsigned short* __restrict__ A,
                                             const unsigned short* __restrict__ W,
                                             const float* __restrict__ bias,
                                             unsigned short* __restrict__ C,
                                             int M, int N, int K) {
    __shared__ char smem[36864];          // loop: As@0 16K | Bs@16K 16K; epi: [128][144] bf16
    const int tid = threadIdx.x;
    // bijective XCD swizzle (all launches have nwg % 8 == 0)
    int nwg = gridDim.x * gridDim.y;
    int orig = blockIdx.y * gridDim.x + blockIdx.x;
    int wg = (orig & 7) * (nwg >> 3) + (orig >> 3);
    int bx = wg % gridDim.x, by = wg / gridDim.x;
    const int m0 = by * 128, n0 = bx * 128;
    const int lane = tid & 63, wv = tid >> 6;
    const int wr = wv >> 1, wc = wv & 1;
    const int lr = lane & 15, lk = lane >> 4;
    char* As = smem;
    char* Bs = smem + 16384;

    f32x4 acc[4][4] = {};

    int so[4], srow[4], sseg[4];
#pragma unroll
    for (int it = 0; it < 4; ++it) {
        int o = it * 4096 + tid * 16;
        so[it] = o;
        srow[it] = o >> 7;
        sseg[it] = ((o >> 4) & 7) ^ (srow[it] & 7);
    }

    for (int k0 = 0; k0 < K; k0 += 64) {
#pragma unroll
        for (int it = 0; it < 4; ++it)
            GLD_LDS16(W + (size_t)(n0 + srow[it]) * K + k0 + sseg[it] * 8, Bs + so[it]);
#pragma unroll
        for (int it = 0; it < 4; ++it)
            GLD_LDS16(A + (size_t)(m0 + srow[it]) * K + k0 + sseg[it] * 8, As + so[it]);
        asm volatile("s_waitcnt vmcnt(0)" ::: "memory");
        __builtin_amdgcn_s_barrier();
#pragma unroll
        for (int kc = 0; kc < 2; ++kc) {
            bf16x8 fA[4], fB[4];
            int slot = kc * 4 + lk;
#pragma unroll
            for (int f = 0; f < 4; ++f) {
                int row = wr * 64 + f * 16 + lr;
                fA[f] = *(const bf16x8*)(As + row * 128 + ((slot ^ (row & 7)) << 4));
                int col = wc * 64 + f * 16 + lr;
                fB[f] = *(const bf16x8*)(Bs + col * 128 + ((slot ^ (col & 7)) << 4));
            }
#pragma unroll
            for (int fi = 0; fi < 4; ++fi)
#pragma unroll
                for (int fj = 0; fj < 4; ++fj)
                    acc[fi][fj] = __builtin_amdgcn_mfma_f32_16x16x32_bf16(
                        fA[fi], fB[fj], acc[fi][fj], 0, 0, 0);
        }
        __builtin_amdgcn_s_barrier();
    }

    // epilogue: bias(+GELU) -> LDS [128][144] bf16 -> vectorized 16B stores
    unsigned short* S = (unsigned short*)smem;
#pragma unroll
    for (int fi = 0; fi < 4; ++fi) {
        int rl = wr * 64 + fi * 16 + lk * 4;
#pragma unroll
        for (int fj = 0; fj < 4; ++fj) {
            int cl = wc * 64 + fj * 16 + lr;
            float bv = bias[n0 + cl];
#pragma unroll
            for (int r = 0; r < 4; ++r) {
                float v = acc[fi][fj][r] + bv;
                if (ACT) v = 0.5f * v * (1.0f + erff(v * 0.70710678118654752f));
                S[(rl + r) * 144 + cl] = f2bf(v);
            }
        }
    }
    __syncthreads();
#pragma unroll
    for (int it = 0; it < 8; ++it) {
        int idx = it * 256 + tid;
        int row = idx >> 4, c8 = (idx & 15) * 8;
        bf16x8 v = *(const bf16x8*)&S[row * 144 + c8];
        *(bf16x8*)&C[(size_t)(m0 + row) * N + n0 + c8] = v;
    }
}

// ---------------------------------------------------------------------------
// Streaming residual + LayerNorm:
//   z = h + c;  h = (z-mean)/sqrt(var+eps)*g + be;  hb = bf16(h)
// One wave per 256-wide row (lane owns 4 consecutive cols), 4 rows per block.
// Pure coalesced float4/bf16x4 traffic; grid = M/4 for max TLP.
__global__ __launch_bounds__(256) void resln(const unsigned short* __restrict__ c,
                                             float* __restrict__ h,
                                             unsigned short* __restrict__ hb,
                                             const float* __restrict__ g,
                                             const float* __restrict__ be) {
    int wv = threadIdx.x >> 6, lane = threadIdx.x & 63;
    size_t row = (size_t)blockIdx.x * 4 + wv;
    size_t off = row * 256 + lane * 4;
    float4 hv = *(const float4*)&h[off];
    bf16x4 cv = *(const bf16x4*)&c[off];
    float4 z = {hv.x + bf2f((unsigned short)cv[0]), hv.y + bf2f((unsigned short)cv[1]),
                hv.z + bf2f((unsigned short)cv[2]), hv.w + bf2f((unsigned short)cv[3])};
    float s = z.x + z.y + z.z + z.w;
    float sq = z.x * z.x + z.y * z.y + z.z * z.z + z.w * z.w;
#pragma unroll
    for (int d = 1; d < 64; d <<= 1) {
        s += __shfl_xor(s, d);
        sq += __shfl_xor(sq, d);
    }
    float mean = s * (1.f / 256.f);
    float var = sq * (1.f / 256.f) - mean * mean;   // biased var
    float inv = 1.0f / sqrtf(var + 1e-5f);
    float4 gv = *(const float4*)&g[lane * 4];
    float4 bv = *(const float4*)&be[lane * 4];
    float4 o;
    o.x = (z.x - mean) * inv * gv.x + bv.x;
    o.y = (z.y - mean) * inv * gv.y + bv.y;
    o.z = (z.z - mean) * inv * gv.z + bv.z;
    o.w = (z.w - mean) * inv * gv.w + bv.w;
    *(float4*)&h[off] = o;
    bf16x4 ob;
    ob[0] = (short)f2bf(o.x); ob[1] = (short)f2bf(o.y);
    ob[2] = (short)f2bf(o.z); ob[3] = (short)f2bf(o.w);
    *(bf16x4*)&hb[off] = ob;
}

// ---------------------------------------------------------------------------
// Causal MHSA: qkv packed bf16 [row][768] (q|k|v), ctx out bf16 [row][256].
__global__ __launch_bounds__(256) void attn_kernel(const unsigned short* __restrict__ qkv,
                                                   unsigned short* __restrict__ ctx) {
    __shared__ float Qs[8 * 260], Ks[8 * 260], Vs[8 * 260];
    int n = blockIdx.x;
    int tid = threadIdx.x;
    size_t base = (size_t)n * 6144;             // 8*768
#pragma unroll
    for (int it = 0; it < 6; ++it) {
        int i4 = it * 256 + tid;                // 0..1535
        int t = i4 / 192;
        int c4 = (i4 - t * 192) * 4;            // 0..764, mult of 4
        const unsigned short* p = qkv + base + (size_t)t * 768 + c4;
        float4 f = {bf2f(p[0]), bf2f(p[1]), bf2f(p[2]), bf2f(p[3])};
        float* dst = (c4 < 256) ? &Qs[t * 260 + c4]
                   : (c4 < 512) ? &Ks[t * 260 + (c4 - 256)]
                                : &Vs[t * 260 + (c4 - 512)];
        *(float4*)dst = f;
    }
    __syncthreads();
    int wid = tid >> 6, lane = tid & 63;
    int t = lane >> 3, s = lane & 7;
    size_t obase = (size_t)n * 2048;
    for (int hh = wid; hh < 8; hh += 4) {
        float acc = 0.f;
        int qb = t * 260 + hh * 32, kb = s * 260 + hh * 32;
#pragma unroll
        for (int jj = 0; jj < 8; ++jj) {
            float4 qv = *(const float4*)&Qs[qb + jj * 4];
            float4 kv = *(const float4*)&Ks[kb + jj * 4];
            acc += qv.x * kv.x + qv.y * kv.y + qv.z * kv.z + qv.w * kv.w;
        }
        acc *= 0.17677669529663687f;            // 1/sqrt(32)
        if (s > t) acc = -1e30f;
        float m = acc;
        m = fmaxf(m, __shfl_xor(m, 1));
        m = fmaxf(m, __shfl_xor(m, 2));
        m = fmaxf(m, __shfl_xor(m, 4));
        float e = __expf(acc - m);
        float sum = e;
        sum += __shfl_xor(sum, 1);
        sum += __shfl_xor(sum, 2);
        sum += __shfl_xor(sum, 4);
        float p = e / sum;
        float a4[4] = {0.f, 0.f, 0.f, 0.f};
#pragma unroll
        for (int s2 = 0; s2 < 8; ++s2) {
            float ps = __shfl(p, (lane & ~7) | s2);
            int vb = s2 * 260 + hh * 32 + s;
#pragma unroll
            for (int r = 0; r < 4; ++r) a4[r] += ps * Vs[vb + 8 * r];
        }
#pragma unroll
        for (int r = 0; r < 4; ++r)
            ctx[obase + t * 256 + hh * 32 + s + 8 * r] = f2bf(a4[r]);
    }
}

// ---------------------------------------------------------------------------
extern "C" void kernel_launch(void* const* d_in, const int* in_sizes, int n_in,
                              void* d_out, int out_size, void* d_ws, size_t ws_size,
                              hipStream_t stream) {
    const float* x   = (const float*)d_in[0];
    const float* Wq  = (const float*)d_in[1];
    const float* bq  = (const float*)d_in[2];
    const float* Wk  = (const float*)d_in[3];
    const float* bk  = (const float*)d_in[4];
    const float* Wv  = (const float*)d_in[5];
    const float* bv  = (const float*)d_in[6];
    const float* Wo  = (const float*)d_in[7];
    const float* bo  = (const float*)d_in[8];
    const float* g1  = (const float*)d_in[9];
    const float* be1 = (const float*)d_in[10];
    const float* W1  = (const float*)d_in[11];
    const float* b1  = (const float*)d_in[12];
    const float* W2  = (const float*)d_in[13];
    const float* b2  = (const float*)d_in[14];
    const float* g2  = (const float*)d_in[15];
    const float* be2 = (const float*)d_in[16];

    // ---- workspace layout (bytes) ----
    // nch=1 end = 305,160,192; nch=2 end = 210,788,352 (ws measured in [264.3, 305.2) MB -> nch=2)
    char* base = (char*)d_ws;
    const size_t O_PE = 0;                          // 16 KB reserved
    const size_t O_W  = 16384;                      // bf16 weights (2 layers)
    const size_t O_BQ = O_W + 2 * 1572864ull;       // packed qkv bias
    const size_t O_H  = O_BQ + 8192;                // h fp32
    const size_t O_HB = O_H + (size_t)TOK * 1024;   // hb bf16
    const size_t O_P1 = O_HB + (size_t)TOK * 512;   // qkv / f1o / wo-out pool
    const int nch = (ws_size >= 305160192ull) ? 1 : 2;
    const int Mc = TOK / nch;
    const size_t O_P2 = O_P1 + (size_t)Mc * 2048;   // ctx / f2-out bf16

    float*          pe   = (float*)(base + O_PE);
    unsigned short* wB   = (unsigned short*)(base + O_W);
    float*          bqkv = (float*)(base + O_BQ);
    float*          h    = (float*)(base + O_H);
    unsigned short* hb   = (unsigned short*)(base + O_HB);
    unsigned short* p1   = (unsigned short*)(base + O_P1);
    unsigned short* ctxb = (unsigned short*)(base + O_P2);

    for (int l = 0; l < 2; ++l) {
        unsigned short* wl = wB + (size_t)l * 786432;
        convertw<<<64,  256, 0, stream>>>(Wq + (size_t)l * 65536,  wl,          16384);
        convertw<<<64,  256, 0, stream>>>(Wk + (size_t)l * 65536,  wl + 65536,  16384);
        convertw<<<64,  256, 0, stream>>>(Wv + (size_t)l * 65536,  wl + 131072, 16384);
        convertw<<<64,  256, 0, stream>>>(Wo + (size_t)l * 65536,  wl + 196608, 16384);
        convertw<<<256, 256, 0, stream>>>(W1 + (size_t)l * 262144, wl + 262144, 65536);
        convertw<<<256, 256, 0, stream>>>(W2 + (size_t)l * 262144, wl + 524288, 65536);
    }
    pack_bias<<<2, 768, 0, stream>>>(bq, bk, bv, bqkv);

    pe_fill<<<8, 256, 0, stream>>>(pe);
    transpose_in<<<dim3(1536, 8, 2), 256, 0, stream>>>(x, pe, h, hb);

    const int gy = Mc / 128;
    for (int l = 0; l < 2; ++l) {
        unsigned short* wqkv = wB + (size_t)l * 786432;
        unsigned short* wo   = wqkv + 196608;
        unsigned short* w1   = wqkv + 262144;
        unsigned short* w2   = wqkv + 524288;

        for (int chn = 0; chn < nch; ++chn) {
            size_t moff = (size_t)chn * Mc;
            unsigned short* hbc = hb + moff * 256;
            float*          hc  = h  + moff * 256;
            // fused qkv projection (N=768)
            mgemm<0><<<dim3(6, gy), 256, 0, stream>>>(hbc, wqkv, bqkv + l * 768, p1, Mc, 768, 256);
            attn_kernel<<<Mc / 8, 256, 0, stream>>>(p1, ctxb);
            // Wo projection -> p1 (qkv dead after attn)
            mgemm<0><<<dim3(2, gy), 256, 0, stream>>>(ctxb, wo, bo + l * 256, p1, Mc, 256, 256);
            // residual + LN1
            resln<<<Mc / 4, 256, 0, stream>>>(p1, hc, hbc, g1 + l * 256, be1 + l * 256);
            // FFN up + GELU -> p1
            mgemm<1><<<dim3(8, gy), 256, 0, stream>>>(hbc, w1, b1 + l * 1024, p1, Mc, 1024, 256);
            // FFN down -> ctxb (dead after wo)
            mgemm<0><<<dim3(2, gy), 256, 0, stream>>>(p1, w2, b2 + l * 256, ctxb, Mc, 256, 1024);
            // residual + LN2
            resln<<<Mc / 4, 256, 0, stream>>>(ctxb, hc, hbc, g2 + l * 256, be2 + l * 256);
        }
    }

    transpose_out<<<dim3(192, 8, 2), 256, 0, stream>>>(h, (float*)d_out);
}

// Round 11
// 810.138 us; speedup vs baseline: 1.2526x; 1.0562x over previous
//
#include <hip/hip_runtime.h>
#include <math.h>

// Problem constants: B=4, T=8, C=d=256, H=W=48, L=2, nh=8, dk=32
#define SEQ   9216          // B*H*W
#define TOK   73728         // SEQ*T

typedef short bf16x8 __attribute__((ext_vector_type(8)));
typedef short bf16x4 __attribute__((ext_vector_type(4)));
typedef float f32x4  __attribute__((ext_vector_type(4)));

#define GLD_LDS16(gsrc, ldst)                                                      \
    __builtin_amdgcn_global_load_lds(                                              \
        (const __attribute__((address_space(1))) unsigned int*)(gsrc),             \
        (__attribute__((address_space(3))) unsigned int*)(ldst), 16, 0, 0)

__device__ __forceinline__ unsigned short f2bf(float f) {
    unsigned u = __builtin_bit_cast(unsigned, f);
    unsigned r = (u + 0x7fffu + ((u >> 16) & 1u)) >> 16;
    return (unsigned short)r;
}
__device__ __forceinline__ float bf2f(unsigned short h) {
    return __builtin_bit_cast(float, (unsigned)h << 16);
}

// ---------------------------------------------------------------------------
__global__ void pe_fill(float* __restrict__ pe) {
    int idx = blockIdx.x * 256 + threadIdx.x;   // 0..2047
    int t = idx >> 8, c = idx & 255;
    int i2 = c & ~1;
    float div = __expf((float)i2 * (-logf(10000.f) / 256.f));
    float ang = (float)t * div;
    pe[idx] = (c & 1) ? cosf(ang) : sinf(ang);
}

__global__ void convertw(const float* __restrict__ src, unsigned short* __restrict__ dst, int n4) {
    int i = blockIdx.x * 256 + threadIdx.x;
    if (i < n4) {
        float4 v = *(const float4*)(src + (size_t)i * 4);
        unsigned short* o = dst + (size_t)i * 4;
        o[0] = f2bf(v.x); o[1] = f2bf(v.y); o[2] = f2bf(v.z); o[3] = f2bf(v.w);
    }
}

__global__ void pack_bias(const float* __restrict__ bq, const float* __restrict__ bk,
                          const float* __restrict__ bv, float* __restrict__ dst) {
    int l = blockIdx.x, i = threadIdx.x;        // block = 768 threads
    float v = (i < 256) ? bq[l * 256 + i] : (i < 512) ? bk[l * 256 + i - 256]
                                                      : bv[l * 256 + i - 512];
    dst[l * 768 + i] = v;
}

// ---------------------------------------------------------------------------
// x (B,T,C,H,W) -> h (n, t, c) fp32 AND hb bf16, with += pe[t,c].
__global__ __launch_bounds__(256) void transpose_in(const float* __restrict__ x,
                                                    const float* __restrict__ pe,
                                                    float* __restrict__ h,
                                                    unsigned short* __restrict__ hb) {
    int bty = blockIdx.x;
    int y = bty % 48; int bt = bty / 48; int t = bt & 7; int b = bt >> 3;
    int c0 = blockIdx.y * 32, w0 = blockIdx.z * 32;
    __shared__ float tile[32][33];
    int tid = threadIdx.x;
    const float* xp = x + ((size_t)(b * 8 + t) * 256) * 2304 + (size_t)y * 48;
    int wl = tid & 31, cl8 = tid >> 5;
#pragma unroll
    for (int it = 0; it < 4; ++it) {
        int c = c0 + it * 8 + cl8;
        int w = w0 + wl;
        if (w < 48) tile[it * 8 + cl8][wl] = xp[(size_t)c * 2304 + w] + pe[t * 256 + c];
    }
    __syncthreads();
    int cl = tid & 31, wl8 = tid >> 5;
#pragma unroll
    for (int it = 0; it < 4; ++it) {
        int w = w0 + it * 8 + wl8;
        int c = c0 + cl;
        if (w < 48) {
            size_t n = (size_t)(b * 48 + y) * 48 + w;
            float val = tile[cl][it * 8 + wl8];
            size_t off = (n * 8 + t) * 256 + c;
            h[off] = val;
            hb[off] = f2bf(val);
        }
    }
}

__global__ __launch_bounds__(256) void transpose_out(const float* __restrict__ h,
                                                     float* __restrict__ out) {
    int by = blockIdx.x; int y = by % 48, b = by / 48;
    int c0 = blockIdx.y * 32, w0 = blockIdx.z * 32;
    __shared__ float tile[32][33];
    int tid = threadIdx.x;
    int cl = tid & 31, wl8 = tid >> 5;
#pragma unroll
    for (int it = 0; it < 4; ++it) {
        int w = w0 + it * 8 + wl8;
        if (w < 48) {
            size_t n = (size_t)(b * 48 + y) * 48 + w;
            tile[it * 8 + wl8][cl] = h[n * 2048 + 1792 + c0 + cl];
        }
    }
    __syncthreads();
    int wl = tid & 31, cl8 = tid >> 5;
#pragma unroll
    for (int it = 0; it < 4; ++it) {
        int c = c0 + it * 8 + cl8;
        int w = w0 + wl;
        if (w < 48)
            out[((size_t)(b * 256 + c) * 48 + y) * 48 + w] = tile[wl][it * 8 + cl8];
    }
}

// ---------------------------------------------------------------------------
// bf16 MFMA GEMM, C bf16 = A @ W^T + bias (opt GELU).
// 128x128 tile, BK=64, 2-PHASE dbuf with COUNTED vmcnt(8) (T3/T4): tile t+1's
// loads issued before compute of tile t and left in flight across the barrier.
// T5 setprio around MFMA cluster. XOR-swizzled LDS, XCD-swizzled grid,
// LDS-restaged vectorized C store.
template <int ACT>
__global__ __launch_bounds__(256) void mgemm(const unsigned short* __restrict__ A,
                                             const unsigned short* __restrict__ W,
                                             const float* __restrict__ bias,
                                             unsigned short* __restrict__ C,
                                             int M, int N, int K) {
    __shared__ char smem[65536];          // A dbuf @0/16K | B dbuf @32K/48K; epi reuse
    const int tid = threadIdx.x;
    // bijective XCD swizzle (all launches have nwg % 8 == 0)
    int nwg = gridDim.x * gridDim.y;
    int orig = blockIdx.y * gridDim.x + blockIdx.x;
    int wg = (orig & 7) * (nwg >> 3) + (orig >> 3);
    int bx = wg % gridDim.x, by = wg / gridDim.x;
    const int m0 = by * 128, n0 = bx * 128;
    const int lane = tid & 63, wv = tid >> 6;
    const int wr = wv >> 1, wc = wv & 1;
    const int lr = lane & 15, lk = lane >> 4;

    f32x4 acc[4][4] = {};

    int so[4], srow[4], sseg[4];
#pragma unroll
    for (int it = 0; it < 4; ++it) {
        int o = it * 4096 + tid * 16;
        so[it] = o;
        srow[it] = o >> 7;
        sseg[it] = ((o >> 4) & 7) ^ (srow[it] & 7);
    }

    const int nt = K >> 6;
    // prologue: stage tile 0 -> buf 0
#pragma unroll
    for (int it = 0; it < 4; ++it)
        GLD_LDS16(W + (size_t)(n0 + srow[it]) * K + sseg[it] * 8, smem + 32768 + so[it]);
#pragma unroll
    for (int it = 0; it < 4; ++it)
        GLD_LDS16(A + (size_t)(m0 + srow[it]) * K + sseg[it] * 8, smem + so[it]);

    int cur = 0;
    for (int t = 0; t < nt; ++t) {
        char* Ac = smem + cur * 16384;
        char* Bc = smem + 32768 + cur * 16384;
        if (t + 1 < nt) {
            const int k1 = (t + 1) << 6;
            char* An = smem + (cur ^ 1) * 16384;
            char* Bn = smem + 32768 + (cur ^ 1) * 16384;
#pragma unroll
            for (int it = 0; it < 4; ++it)
                GLD_LDS16(W + (size_t)(n0 + srow[it]) * K + k1 + sseg[it] * 8, Bn + so[it]);
#pragma unroll
            for (int it = 0; it < 4; ++it)
                GLD_LDS16(A + (size_t)(m0 + srow[it]) * K + k1 + sseg[it] * 8, An + so[it]);
            // tile t's 8 loads done; t+1's 8 stay in flight across the barrier
            asm volatile("s_waitcnt vmcnt(8)" ::: "memory");
        } else {
            asm volatile("s_waitcnt vmcnt(0)" ::: "memory");
        }
        __builtin_amdgcn_s_barrier();
        __builtin_amdgcn_s_setprio(1);
#pragma unroll
        for (int kc = 0; kc < 2; ++kc) {
            bf16x8 fA[4], fB[4];
            int slot = kc * 4 + lk;
#pragma unroll
            for (int f = 0; f < 4; ++f) {
                int row = wr * 64 + f * 16 + lr;
                fA[f] = *(const bf16x8*)(Ac + row * 128 + ((slot ^ (row & 7)) << 4));
                int col = wc * 64 + f * 16 + lr;
                fB[f] = *(const bf16x8*)(Bc + col * 128 + ((slot ^ (col & 7)) << 4));
            }
#pragma unroll
            for (int fi = 0; fi < 4; ++fi)
#pragma unroll
                for (int fj = 0; fj < 4; ++fj)
                    acc[fi][fj] = __builtin_amdgcn_mfma_f32_16x16x32_bf16(
                        fA[fi], fB[fj], acc[fi][fj], 0, 0, 0);
        }
        __builtin_amdgcn_s_setprio(0);
        __builtin_amdgcn_s_barrier();
        cur ^= 1;
    }

    // epilogue: bias(+GELU) -> LDS [128][144] bf16 -> vectorized 16B stores
    unsigned short* S = (unsigned short*)smem;
#pragma unroll
    for (int fi = 0; fi < 4; ++fi) {
        int rl = wr * 64 + fi * 16 + lk * 4;
#pragma unroll
        for (int fj = 0; fj < 4; ++fj) {
            int cl = wc * 64 + fj * 16 + lr;
            float bv = bias[n0 + cl];
#pragma unroll
            for (int r = 0; r < 4; ++r) {
                float v = acc[fi][fj][r] + bv;
                if (ACT) v = 0.5f * v * (1.0f + erff(v * 0.70710678118654752f));
                S[(rl + r) * 144 + cl] = f2bf(v);
            }
        }
    }
    __syncthreads();
#pragma unroll
    for (int it = 0; it < 8; ++it) {
        int idx = it * 256 + tid;
        int row = idx >> 4, c8 = (idx & 15) * 8;
        bf16x8 v = *(const bf16x8*)&S[row * 144 + c8];
        *(bf16x8*)&C[(size_t)(m0 + row) * N + n0 + c8] = v;
    }
}

// ---------------------------------------------------------------------------
// Streaming residual + LayerNorm:
//   z = h + c;  h = (z-mean)/sqrt(var+eps)*g + be;  hb = bf16(h)
// One wave per 256-wide row (lane owns 4 consecutive cols), 4 rows per block.
__global__ __launch_bounds__(256) void resln(const unsigned short* __restrict__ c,
                                             float* __restrict__ h,
                                             unsigned short* __restrict__ hb,
                                             const float* __restrict__ g,
                                             const float* __restrict__ be) {
    int wv = threadIdx.x >> 6, lane = threadIdx.x & 63;
    size_t row = (size_t)blockIdx.x * 4 + wv;
    size_t off = row * 256 + lane * 4;
    float4 hv = *(const float4*)&h[off];
    bf16x4 cv = *(const bf16x4*)&c[off];
    float4 z = {hv.x + bf2f((unsigned short)cv[0]), hv.y + bf2f((unsigned short)cv[1]),
                hv.z + bf2f((unsigned short)cv[2]), hv.w + bf2f((unsigned short)cv[3])};
    float s = z.x + z.y + z.z + z.w;
    float sq = z.x * z.x + z.y * z.y + z.z * z.z + z.w * z.w;
#pragma unroll
    for (int d = 1; d < 64; d <<= 1) {
        s += __shfl_xor(s, d);
        sq += __shfl_xor(sq, d);
    }
    float mean = s * (1.f / 256.f);
    float var = sq * (1.f / 256.f) - mean * mean;   // biased var
    float inv = 1.0f / sqrtf(var + 1e-5f);
    float4 gv = *(const float4*)&g[lane * 4];
    float4 bv = *(const float4*)&be[lane * 4];
    float4 o;
    o.x = (z.x - mean) * inv * gv.x + bv.x;
    o.y = (z.y - mean) * inv * gv.y + bv.y;
    o.z = (z.z - mean) * inv * gv.z + bv.z;
    o.w = (z.w - mean) * inv * gv.w + bv.w;
    *(float4*)&h[off] = o;
    bf16x4 ob;
    ob[0] = (short)f2bf(o.x); ob[1] = (short)f2bf(o.y);
    ob[2] = (short)f2bf(o.z); ob[3] = (short)f2bf(o.w);
    *(bf16x4*)&hb[off] = ob;
}

// ---------------------------------------------------------------------------
// Causal MHSA: qkv packed bf16 [row][768] (q|k|v), ctx out bf16 [row][256].
__global__ __launch_bounds__(256) void attn_kernel(const unsigned short* __restrict__ qkv,
                                                   unsigned short* __restrict__ ctx) {
    __shared__ float Qs[8 * 260], Ks[8 * 260], Vs[8 * 260];
    int n = blockIdx.x;
    int tid = threadIdx.x;
    size_t base = (size_t)n * 6144;             // 8*768
#pragma unroll
    for (int it = 0; it < 6; ++it) {
        int i4 = it * 256 + tid;                // 0..1535
        int t = i4 / 192;
        int c4 = (i4 - t * 192) * 4;            // 0..764, mult of 4
        const unsigned short* p = qkv + base + (size_t)t * 768 + c4;
        float4 f = {bf2f(p[0]), bf2f(p[1]), bf2f(p[2]), bf2f(p[3])};
        float* dst = (c4 < 256) ? &Qs[t * 260 + c4]
                   : (c4 < 512) ? &Ks[t * 260 + (c4 - 256)]
                                : &Vs[t * 260 + (c4 - 512)];
        *(float4*)dst = f;
    }
    __syncthreads();
    int wid = tid >> 6, lane = tid & 63;
    int t = lane >> 3, s = lane & 7;
    size_t obase = (size_t)n * 2048;
    for (int hh = wid; hh < 8; hh += 4) {
        float acc = 0.f;
        int qb = t * 260 + hh * 32, kb = s * 260 + hh * 32;
#pragma unroll
        for (int jj = 0; jj < 8; ++jj) {
            float4 qv = *(const float4*)&Qs[qb + jj * 4];
            float4 kv = *(const float4*)&Ks[kb + jj * 4];
            acc += qv.x * kv.x + qv.y * kv.y + qv.z * kv.z + qv.w * kv.w;
        }
        acc *= 0.17677669529663687f;            // 1/sqrt(32)
        if (s > t) acc = -1e30f;
        float m = acc;
        m = fmaxf(m, __shfl_xor(m, 1));
        m = fmaxf(m, __shfl_xor(m, 2));
        m = fmaxf(m, __shfl_xor(m, 4));
        float e = __expf(acc - m);
        float sum = e;
        sum += __shfl_xor(sum, 1);
        sum += __shfl_xor(sum, 2);
        sum += __shfl_xor(sum, 4);
        float p = e / sum;
        float a4[4] = {0.f, 0.f, 0.f, 0.f};
#pragma unroll
        for (int s2 = 0; s2 < 8; ++s2) {
            float ps = __shfl(p, (lane & ~7) | s2);
            int vb = s2 * 260 + hh * 32 + s;
#pragma unroll
            for (int r = 0; r < 4; ++r) a4[r] += ps * Vs[vb + 8 * r];
        }
#pragma unroll
        for (int r = 0; r < 4; ++r)
            ctx[obase + t * 256 + hh * 32 + s + 8 * r] = f2bf(a4[r]);
    }
}

// ---------------------------------------------------------------------------
extern "C" void kernel_launch(void* const* d_in, const int* in_sizes, int n_in,
                              void* d_out, int out_size, void* d_ws, size_t ws_size,
                              hipStream_t stream) {
    const float* x   = (const float*)d_in[0];
    const float* Wq  = (const float*)d_in[1];
    const float* bq  = (const float*)d_in[2];
    const float* Wk  = (const float*)d_in[3];
    const float* bk  = (const float*)d_in[4];
    const float* Wv  = (const float*)d_in[5];
    const float* bv  = (const float*)d_in[6];
    const float* Wo  = (const float*)d_in[7];
    const float* bo  = (const float*)d_in[8];
    const float* g1  = (const float*)d_in[9];
    const float* be1 = (const float*)d_in[10];
    const float* W1  = (const float*)d_in[11];
    const float* b1  = (const float*)d_in[12];
    const float* W2  = (const float*)d_in[13];
    const float* b2  = (const float*)d_in[14];
    const float* g2  = (const float*)d_in[15];
    const float* be2 = (const float*)d_in[16];

    // ---- workspace layout (bytes) ----
    // nch=1 end = 305,160,192; nch=2 end = 210,788,352 (ws measured in [264.3, 305.2) MB -> nch=2)
    char* base = (char*)d_ws;
    const size_t O_PE = 0;                          // 16 KB reserved
    const size_t O_W  = 16384;                      // bf16 weights (2 layers)
    const size_t O_BQ = O_W + 2 * 1572864ull;       // packed qkv bias
    const size_t O_H  = O_BQ + 8192;                // h fp32
    const size_t O_HB = O_H + (size_t)TOK * 1024;   // hb bf16
    const size_t O_P1 = O_HB + (size_t)TOK * 512;   // qkv / f1o / wo-out pool
    const int nch = (ws_size >= 305160192ull) ? 1 : 2;
    const int Mc = TOK / nch;
    const size_t O_P2 = O_P1 + (size_t)Mc * 2048;   // ctx / f2-out bf16

    float*          pe   = (float*)(base + O_PE);
    unsigned short* wB   = (unsigned short*)(base + O_W);
    float*          bqkv = (float*)(base + O_BQ);
    float*          h    = (float*)(base + O_H);
    unsigned short* hb   = (unsigned short*)(base + O_HB);
    unsigned short* p1   = (unsigned short*)(base + O_P1);
    unsigned short* ctxb = (unsigned short*)(base + O_P2);

    for (int l = 0; l < 2; ++l) {
        unsigned short* wl = wB + (size_t)l * 786432;
        convertw<<<64,  256, 0, stream>>>(Wq + (size_t)l * 65536,  wl,          16384);
        convertw<<<64,  256, 0, stream>>>(Wk + (size_t)l * 65536,  wl + 65536,  16384);
        convertw<<<64,  256, 0, stream>>>(Wv + (size_t)l * 65536,  wl + 131072, 16384);
        convertw<<<64,  256, 0, stream>>>(Wo + (size_t)l * 65536,  wl + 196608, 16384);
        convertw<<<256, 256, 0, stream>>>(W1 + (size_t)l * 262144, wl + 262144, 65536);
        convertw<<<256, 256, 0, stream>>>(W2 + (size_t)l * 262144, wl + 524288, 65536);
    }
    pack_bias<<<2, 768, 0, stream>>>(bq, bk, bv, bqkv);

    pe_fill<<<8, 256, 0, stream>>>(pe);
    transpose_in<<<dim3(1536, 8, 2), 256, 0, stream>>>(x, pe, h, hb);

    const int gy = Mc / 128;
    for (int l = 0; l < 2; ++l) {
        unsigned short* wqkv = wB + (size_t)l * 786432;
        unsigned short* wo   = wqkv + 196608;
        unsigned short* w1   = wqkv + 262144;
        unsigned short* w2   = wqkv + 524288;

        for (int chn = 0; chn < nch; ++chn) {
            size_t moff = (size_t)chn * Mc;
            unsigned short* hbc = hb + moff * 256;
            float*          hc  = h  + moff * 256;
            // fused qkv projection (N=768)
            mgemm<0><<<dim3(6, gy), 256, 0, stream>>>(hbc, wqkv, bqkv + l * 768, p1, Mc, 768, 256);
            attn_kernel<<<Mc / 8, 256, 0, stream>>>(p1, ctxb);
            // Wo projection -> p1 (qkv dead after attn)
            mgemm<0><<<dim3(2, gy), 256, 0, stream>>>(ctxb, wo, bo + l * 256, p1, Mc, 256, 256);
            // residual + LN1
            resln<<<Mc / 4, 256, 0, stream>>>(p1, hc, hbc, g1 + l * 256, be1 + l * 256);
            // FFN up + GELU -> p1
            mgemm<1><<<dim3(8, gy), 256, 0, stream>>>(hbc, w1, b1 + l * 1024, p1, Mc, 1024, 256);
            // FFN down -> ctxb (dead after wo)
            mgemm<0><<<dim3(2, gy), 256, 0, stream>>>(p1, w2, b2 + l * 256, ctxb, Mc, 256, 1024);
            // residual + LN2
            resln<<<Mc / 4, 256, 0, stream>>>(ctxb, hc, hbc, g2 + l * 256, be2 + l * 256);
        }
    }

    transpose_out<<<dim3(192, 8, 2), 256, 0, stream>>>(h, (float*)d_out);
}

// Round 13
// 770.647 us; speedup vs baseline: 1.3168x; 1.0512x over previous
//
#include <hip/hip_runtime.h>
#include <math.h>

// Problem constants: B=4, T=8, C=d=256, H=W=48, L=2, nh=8, dk=32
#define SEQ   9216          // B*H*W
#define TOK   73728         // SEQ*T

typedef short bf16x8 __attribute__((ext_vector_type(8)));
typedef short bf16x4 __attribute__((ext_vector_type(4)));
typedef float f32x4  __attribute__((ext_vector_type(4)));

#define GLD_LDS16(gsrc, ldst)                                                      \
    __builtin_amdgcn_global_load_lds(                                              \
        (const __attribute__((address_space(1))) unsigned int*)(gsrc),             \
        (__attribute__((address_space(3))) unsigned int*)(ldst), 16, 0, 0)

__device__ __forceinline__ unsigned short f2bf(float f) {
    unsigned u = __builtin_bit_cast(unsigned, f);
    unsigned r = (u + 0x7fffu + ((u >> 16) & 1u)) >> 16;
    return (unsigned short)r;
}
__device__ __forceinline__ float bf2f(unsigned short h) {
    return __builtin_bit_cast(float, (unsigned)h << 16);
}

// ---------------------------------------------------------------------------
__global__ void pe_fill(float* __restrict__ pe) {
    int idx = blockIdx.x * 256 + threadIdx.x;   // 0..2047
    int t = idx >> 8, c = idx & 255;
    int i2 = c & ~1;
    float div = __expf((float)i2 * (-logf(10000.f) / 256.f));
    float ang = (float)t * div;
    pe[idx] = (c & 1) ? cosf(ang) : sinf(ang);
}

__global__ void convertw(const float* __restrict__ src, unsigned short* __restrict__ dst, int n4) {
    int i = blockIdx.x * 256 + threadIdx.x;
    if (i < n4) {
        float4 v = *(const float4*)(src + (size_t)i * 4);
        unsigned short* o = dst + (size_t)i * 4;
        o[0] = f2bf(v.x); o[1] = f2bf(v.y); o[2] = f2bf(v.z); o[3] = f2bf(v.w);
    }
}

__global__ void pack_bias(const float* __restrict__ bq, const float* __restrict__ bk,
                          const float* __restrict__ bv, float* __restrict__ dst) {
    int l = blockIdx.x, i = threadIdx.x;        // block = 768 threads
    float v = (i < 256) ? bq[l * 256 + i] : (i < 512) ? bk[l * 256 + i - 256]
                                                      : bv[l * 256 + i - 512];
    dst[l * 768 + i] = v;
}

// ---------------------------------------------------------------------------
// x (B,T,C,H,W) -> h (n, t, c) fp32 AND hb bf16, with += pe[t,c].
__global__ __launch_bounds__(256) void transpose_in(const float* __restrict__ x,
                                                    const float* __restrict__ pe,
                                                    float* __restrict__ h,
                                                    unsigned short* __restrict__ hb) {
    int bty = blockIdx.x;
    int y = bty % 48; int bt = bty / 48; int t = bt & 7; int b = bt >> 3;
    int c0 = blockIdx.y * 32, w0 = blockIdx.z * 32;
    __shared__ float tile[32][33];
    int tid = threadIdx.x;
    const float* xp = x + ((size_t)(b * 8 + t) * 256) * 2304 + (size_t)y * 48;
    int wl = tid & 31, cl8 = tid >> 5;
#pragma unroll
    for (int it = 0; it < 4; ++it) {
        int c = c0 + it * 8 + cl8;
        int w = w0 + wl;
        if (w < 48) tile[it * 8 + cl8][wl] = xp[(size_t)c * 2304 + w] + pe[t * 256 + c];
    }
    __syncthreads();
    int cl = tid & 31, wl8 = tid >> 5;
#pragma unroll
    for (int it = 0; it < 4; ++it) {
        int w = w0 + it * 8 + wl8;
        int c = c0 + cl;
        if (w < 48) {
            size_t n = (size_t)(b * 48 + y) * 48 + w;
            float val = tile[cl][it * 8 + wl8];
            size_t off = (n * 8 + t) * 256 + c;
            h[off] = val;
            hb[off] = f2bf(val);
        }
    }
}

__global__ __launch_bounds__(256) void transpose_out(const float* __restrict__ h,
                                                     float* __restrict__ out) {
    int by = blockIdx.x; int y = by % 48, b = by / 48;
    int c0 = blockIdx.y * 32, w0 = blockIdx.z * 32;
    __shared__ float tile[32][33];
    int tid = threadIdx.x;
    int cl = tid & 31, wl8 = tid >> 5;
#pragma unroll
    for (int it = 0; it < 4; ++it) {
        int w = w0 + it * 8 + wl8;
        if (w < 48) {
            size_t n = (size_t)(b * 48 + y) * 48 + w;
            tile[it * 8 + wl8][cl] = h[n * 2048 + 1792 + c0 + cl];
        }
    }
    __syncthreads();
    int wl = tid & 31, cl8 = tid >> 5;
#pragma unroll
    for (int it = 0; it < 4; ++it) {
        int c = c0 + it * 8 + cl8;
        int w = w0 + wl;
        if (w < 48)
            out[((size_t)(b * 256 + c) * 48 + y) * 48 + w] = tile[wl][it * 8 + cl8];
    }
}

// ---------------------------------------------------------------------------
// bf16 MFMA GEMM, C bf16 = A @ W^T + bias (opt GELU).
// 128x128 tile, BK=32, DOUBLE-buffer in 32 KB (A0@0 A1@8K B0@16K B1@24K) so
// LDS stays 36 KB -> 4 blocks/CU AND counted vmcnt(4) pipelining (T3/T4):
// next K-step's 4 loads stay in flight across the barrier. Swizzle for 64-B
// rows: slot ^= (row>>1)&3 (banks distinct for row mod 8 -> 2-way = free),
// applied on gld_lds SOURCE and LDS READ (both-sides rule). T5 setprio.
// XCD-swizzled grid, LDS-restaged vectorized C store.
template <int ACT>
__global__ __launch_bounds__(256) void mgemm(const unsigned short* __restrict__ A,
                                             const unsigned short* __restrict__ W,
                                             const float* __restrict__ bias,
                                             unsigned short* __restrict__ C,
                                             int M, int N, int K) {
    __shared__ char smem[36864];          // loop: 32 KB dbuf; epi: [128][144] bf16
    const int tid = threadIdx.x;
    // bijective XCD swizzle (all launches have nwg % 8 == 0)
    int nwg = gridDim.x * gridDim.y;
    int orig = blockIdx.y * gridDim.x + blockIdx.x;
    int wg = (orig & 7) * (nwg >> 3) + (orig >> 3);
    int bx = wg % gridDim.x, by = wg / gridDim.x;
    const int m0 = by * 128, n0 = bx * 128;
    const int lane = tid & 63, wv = tid >> 6;
    const int wr = wv >> 1, wc = wv & 1;
    const int lr = lane & 15, lk = lane >> 4;

    f32x4 acc[4][4] = {};

    // staging geometry: 2 x 16B per thread per operand per K-step
    int so[2], srow[2], sseg[2];
#pragma unroll
    for (int it = 0; it < 2; ++it) {
        int o = it * 4096 + tid * 16;     // linear byte offset in 8 KB tile
        so[it] = o;
        srow[it] = o >> 6;                // row 0..127 (64 B rows)
        sseg[it] = ((o >> 4) & 3) ^ ((srow[it] >> 1) & 3);   // source 16B slot
    }

    const int nt = K >> 5;
    // prologue: stage K-step 0 -> buf 0
#pragma unroll
    for (int it = 0; it < 2; ++it)
        GLD_LDS16(W + (size_t)(n0 + srow[it]) * K + sseg[it] * 8, smem + 16384 + so[it]);
#pragma unroll
    for (int it = 0; it < 2; ++it)
        GLD_LDS16(A + (size_t)(m0 + srow[it]) * K + sseg[it] * 8, smem + so[it]);

    int cur = 0;
    for (int t = 0; t < nt; ++t) {
        char* Ac = smem + cur * 8192;
        char* Bc = smem + 16384 + cur * 8192;
        if (t + 1 < nt) {
            const int k1 = (t + 1) << 5;
            char* An = smem + (cur ^ 1) * 8192;
            char* Bn = smem + 16384 + (cur ^ 1) * 8192;
#pragma unroll
            for (int it = 0; it < 2; ++it)
                GLD_LDS16(W + (size_t)(n0 + srow[it]) * K + k1 + sseg[it] * 8, Bn + so[it]);
#pragma unroll
            for (int it = 0; it < 2; ++it)
                GLD_LDS16(A + (size_t)(m0 + srow[it]) * K + k1 + sseg[it] * 8, An + so[it]);
            // step t's 4 loads done; step t+1's 4 stay in flight across barrier
            asm volatile("s_waitcnt vmcnt(4)" ::: "memory");
        } else {
            asm volatile("s_waitcnt vmcnt(0)" ::: "memory");
        }
        __builtin_amdgcn_s_barrier();
        __builtin_amdgcn_s_setprio(1);
        {
            bf16x8 fA[4], fB[4];
#pragma unroll
            for (int f = 0; f < 4; ++f) {
                int row = wr * 64 + f * 16 + lr;
                fA[f] = *(const bf16x8*)(Ac + row * 64 + ((lk ^ ((row >> 1) & 3)) << 4));
                int col = wc * 64 + f * 16 + lr;
                fB[f] = *(const bf16x8*)(Bc + col * 64 + ((lk ^ ((col >> 1) & 3)) << 4));
            }
#pragma unroll
            for (int fi = 0; fi < 4; ++fi)
#pragma unroll
                for (int fj = 0; fj < 4; ++fj)
                    acc[fi][fj] = __builtin_amdgcn_mfma_f32_16x16x32_bf16(
                        fA[fi], fB[fj], acc[fi][fj], 0, 0, 0);
        }
        __builtin_amdgcn_s_setprio(0);
        __builtin_amdgcn_s_barrier();
        cur ^= 1;
    }

    // epilogue: bias(+GELU) -> LDS [128][144] bf16 -> vectorized 16B stores
    unsigned short* S = (unsigned short*)smem;
#pragma unroll
    for (int fi = 0; fi < 4; ++fi) {
        int rl = wr * 64 + fi * 16 + lk * 4;
#pragma unroll
        for (int fj = 0; fj < 4; ++fj) {
            int cl = wc * 64 + fj * 16 + lr;
            float bv = bias[n0 + cl];
#pragma unroll
            for (int r = 0; r < 4; ++r) {
                float v = acc[fi][fj][r] + bv;
                if (ACT) v = 0.5f * v * (1.0f + erff(v * 0.70710678118654752f));
                S[(rl + r) * 144 + cl] = f2bf(v);
            }
        }
    }
    __syncthreads();
#pragma unroll
    for (int it = 0; it < 8; ++it) {
        int idx = it * 256 + tid;
        int row = idx >> 4, c8 = (idx & 15) * 8;
        bf16x8 v = *(const bf16x8*)&S[row * 144 + c8];
        *(bf16x8*)&C[(size_t)(m0 + row) * N + n0 + c8] = v;
    }
}

// ---------------------------------------------------------------------------
// Streaming residual + LayerNorm:
//   z = h + c;  h = (z-mean)/sqrt(var+eps)*g + be;  hb = bf16(h)
// One wave per 256-wide row (lane owns 4 consecutive cols), 4 rows per block.
__global__ __launch_bounds__(256) void resln(const unsigned short* __restrict__ c,
                                             float* __restrict__ h,
                                             unsigned short* __restrict__ hb,
                                             const float* __restrict__ g,
                                             const float* __restrict__ be) {
    int wv = threadIdx.x >> 6, lane = threadIdx.x & 63;
    size_t row = (size_t)blockIdx.x * 4 + wv;
    size_t off = row * 256 + lane * 4;
    float4 hv = *(const float4*)&h[off];
    bf16x4 cv = *(const bf16x4*)&c[off];
    float4 z = {hv.x + bf2f((unsigned short)cv[0]), hv.y + bf2f((unsigned short)cv[1]),
                hv.z + bf2f((unsigned short)cv[2]), hv.w + bf2f((unsigned short)cv[3])};
    float s = z.x + z.y + z.z + z.w;
    float sq = z.x * z.x + z.y * z.y + z.z * z.z + z.w * z.w;
#pragma unroll
    for (int d = 1; d < 64; d <<= 1) {
        s += __shfl_xor(s, d);
        sq += __shfl_xor(sq, d);
    }
    float mean = s * (1.f / 256.f);
    float var = sq * (1.f / 256.f) - mean * mean;   // biased var
    float inv = 1.0f / sqrtf(var + 1e-5f);
    float4 gv = *(const float4*)&g[lane * 4];
    float4 bv = *(const float4*)&be[lane * 4];
    float4 o;
    o.x = (z.x - mean) * inv * gv.x + bv.x;
    o.y = (z.y - mean) * inv * gv.y + bv.y;
    o.z = (z.z - mean) * inv * gv.z + bv.z;
    o.w = (z.w - mean) * inv * gv.w + bv.w;
    *(float4*)&h[off] = o;
    bf16x4 ob;
    ob[0] = (short)f2bf(o.x); ob[1] = (short)f2bf(o.y);
    ob[2] = (short)f2bf(o.z); ob[3] = (short)f2bf(o.w);
    *(bf16x4*)&hb[off] = ob;
}

// ---------------------------------------------------------------------------
// Causal MHSA: qkv packed bf16 [row][768] (q|k|v), ctx out bf16 [row][256].
__global__ __launch_bounds__(256) void attn_kernel(const unsigned short* __restrict__ qkv,
                                                   unsigned short* __restrict__ ctx) {
    __shared__ float Qs[8 * 260], Ks[8 * 260], Vs[8 * 260];
    int n = blockIdx.x;
    int tid = threadIdx.x;
    size_t base = (size_t)n * 6144;             // 8*768
#pragma unroll
    for (int it = 0; it < 6; ++it) {
        int i4 = it * 256 + tid;                // 0..1535
        int t = i4 / 192;
        int c4 = (i4 - t * 192) * 4;            // 0..764, mult of 4
        const unsigned short* p = qkv + base + (size_t)t * 768 + c4;
        float4 f = {bf2f(p[0]), bf2f(p[1]), bf2f(p[2]), bf2f(p[3])};
        float* dst = (c4 < 256) ? &Qs[t * 260 + c4]
                   : (c4 < 512) ? &Ks[t * 260 + (c4 - 256)]
                                : &Vs[t * 260 + (c4 - 512)];
        *(float4*)dst = f;
    }
    __syncthreads();
    int wid = tid >> 6, lane = tid & 63;
    int t = lane >> 3, s = lane & 7;
    size_t obase = (size_t)n * 2048;
    for (int hh = wid; hh < 8; hh += 4) {
        float acc = 0.f;
        int qb = t * 260 + hh * 32, kb = s * 260 + hh * 32;
#pragma unroll
        for (int jj = 0; jj < 8; ++jj) {
            float4 qv = *(const float4*)&Qs[qb + jj * 4];
            float4 kv = *(const float4*)&Ks[kb + jj * 4];
            acc += qv.x * kv.x + qv.y * kv.y + qv.z * kv.z + qv.w * kv.w;
        }
        acc *= 0.17677669529663687f;            // 1/sqrt(32)
        if (s > t) acc = -1e30f;
        float m = acc;
        m = fmaxf(m, __shfl_xor(m, 1));
        m = fmaxf(m, __shfl_xor(m, 2));
        m = fmaxf(m, __shfl_xor(m, 4));
        float e = __expf(acc - m);
        float sum = e;
        sum += __shfl_xor(sum, 1);
        sum += __shfl_xor(sum, 2);
        sum += __shfl_xor(sum, 4);
        float p = e / sum;
        float a4[4] = {0.f, 0.f, 0.f, 0.f};
#pragma unroll
        for (int s2 = 0; s2 < 8; ++s2) {
            float ps = __shfl(p, (lane & ~7) | s2);
            int vb = s2 * 260 + hh * 32 + s;
#pragma unroll
            for (int r = 0; r < 4; ++r) a4[r] += ps * Vs[vb + 8 * r];
        }
#pragma unroll
        for (int r = 0; r < 4; ++r)
            ctx[obase + t * 256 + hh * 32 + s + 8 * r] = f2bf(a4[r]);
    }
}

// ---------------------------------------------------------------------------
extern "C" void kernel_launch(void* const* d_in, const int* in_sizes, int n_in,
                              void* d_out, int out_size, void* d_ws, size_t ws_size,
                              hipStream_t stream) {
    const float* x   = (const float*)d_in[0];
    const float* Wq  = (const float*)d_in[1];
    const float* bq  = (const float*)d_in[2];
    const float* Wk  = (const float*)d_in[3];
    const float* bk  = (const float*)d_in[4];
    const float* Wv  = (const float*)d_in[5];
    const float* bv  = (const float*)d_in[6];
    const float* Wo  = (const float*)d_in[7];
    const float* bo  = (const float*)d_in[8];
    const float* g1  = (const float*)d_in[9];
    const float* be1 = (const float*)d_in[10];
    const float* W1  = (const float*)d_in[11];
    const float* b1  = (const float*)d_in[12];
    const float* W2  = (const float*)d_in[13];
    const float* b2  = (const float*)d_in[14];
    const float* g2  = (const float*)d_in[15];
    const float* be2 = (const float*)d_in[16];

    // ---- workspace layout (bytes) ----
    // nch=1 end = 305,160,192; nch=2 end = 210,788,352 (ws measured in [264.3, 305.2) MB -> nch=2)
    char* base = (char*)d_ws;
    const size_t O_PE = 0;                          // 16 KB reserved
    const size_t O_W  = 16384;                      // bf16 weights (2 layers)
    const size_t O_BQ = O_W + 2 * 1572864ull;       // packed qkv bias
    const size_t O_H  = O_BQ + 8192;                // h fp32
    const size_t O_HB = O_H + (size_t)TOK * 1024;   // hb bf16
    const size_t O_P1 = O_HB + (size_t)TOK * 512;   // qkv / f1o / wo-out pool
    const int nch = (ws_size >= 305160192ull) ? 1 : 2;
    const int Mc = TOK / nch;
    const size_t O_P2 = O_P1 + (size_t)Mc * 2048;   // ctx / f2-out bf16

    float*          pe   = (float*)(base + O_PE);
    unsigned short* wB   = (unsigned short*)(base + O_W);
    float*          bqkv = (float*)(base + O_BQ);
    float*          h    = (float*)(base + O_H);
    unsigned short* hb   = (unsigned short*)(base + O_HB);
    unsigned short* p1   = (unsigned short*)(base + O_P1);
    unsigned short* ctxb = (unsigned short*)(base + O_P2);

    for (int l = 0; l < 2; ++l) {
        unsigned short* wl = wB + (size_t)l * 786432;
        convertw<<<64,  256, 0, stream>>>(Wq + (size_t)l * 65536,  wl,          16384);
        convertw<<<64,  256, 0, stream>>>(Wk + (size_t)l * 65536,  wl + 65536,  16384);
        convertw<<<64,  256, 0, stream>>>(Wv + (size_t)l * 65536,  wl + 131072, 16384);
        convertw<<<64,  256, 0, stream>>>(Wo + (size_t)l * 65536,  wl + 196608, 16384);
        convertw<<<256, 256, 0, stream>>>(W1 + (size_t)l * 262144, wl + 262144, 65536);
        convertw<<<256, 256, 0, stream>>>(W2 + (size_t)l * 262144, wl + 524288, 65536);
    }
    pack_bias<<<2, 768, 0, stream>>>(bq, bk, bv, bqkv);

    pe_fill<<<8, 256, 0, stream>>>(pe);
    transpose_in<<<dim3(1536, 8, 2), 256, 0, stream>>>(x, pe, h, hb);

    const int gy = Mc / 128;
    for (int l = 0; l < 2; ++l) {
        unsigned short* wqkv = wB + (size_t)l * 786432;
        unsigned short* wo   = wqkv + 196608;
        unsigned short* w1   = wqkv + 262144;
        unsigned short* w2   = wqkv + 524288;

        for (int chn = 0; chn < nch; ++chn) {
            size_t moff = (size_t)chn * Mc;
            unsigned short* hbc = hb + moff * 256;
            float*          hc  = h  + moff * 256;
            // fused qkv projection (N=768)
            mgemm<0><<<dim3(6, gy), 256, 0, stream>>>(hbc, wqkv, bqkv + l * 768, p1, Mc, 768, 256);
            attn_kernel<<<Mc / 8, 256, 0, stream>>>(p1, ctxb);
            // Wo projection -> p1 (qkv dead after attn)
            mgemm<0><<<dim3(2, gy), 256, 0, stream>>>(ctxb, wo, bo + l * 256, p1, Mc, 256, 256);
            // residual + LN1
            resln<<<Mc / 4, 256, 0, stream>>>(p1, hc, hbc, g1 + l * 256, be1 + l * 256);
            // FFN up + GELU -> p1
            mgemm<1><<<dim3(8, gy), 256, 0, stream>>>(hbc, w1, b1 + l * 1024, p1, Mc, 1024, 256);
            // FFN down -> ctxb (dead after wo)
            mgemm<0><<<dim3(2, gy), 256, 0, stream>>>(p1, w2, b2 + l * 256, ctxb, Mc, 256, 1024);
            // residual + LN2
            resln<<<Mc / 4, 256, 0, stream>>>(ctxb, hc, hbc, g2 + l * 256, be2 + l * 256);
        }
    }

    transpose_out<<<dim3(192, 8, 2), 256, 0, stream>>>(h, (float*)d_out);
}

// Round 14
// 603.074 us; speedup vs baseline: 1.6827x; 1.2779x over previous
//
#include <hip/hip_runtime.h>
#include <math.h>

// Problem constants: B=4, T=8, C=d=256, H=W=48, L=2, nh=8, dk=32
#define SEQ   9216          // B*H*W
#define TOK   73728         // SEQ*T

typedef short bf16x8 __attribute__((ext_vector_type(8)));
typedef short bf16x4 __attribute__((ext_vector_type(4)));
typedef float f32x4  __attribute__((ext_vector_type(4)));

#define GLD_LDS16(gsrc, ldst)                                                      \
    __builtin_amdgcn_global_load_lds(                                              \
        (const __attribute__((address_space(1))) unsigned int*)(gsrc),             \
        (__attribute__((address_space(3))) unsigned int*)(ldst), 16, 0, 0)

__device__ __forceinline__ unsigned short f2bf(float f) {
    unsigned u = __builtin_bit_cast(unsigned, f);
    unsigned r = (u + 0x7fffu + ((u >> 16) & 1u)) >> 16;
    return (unsigned short)r;
}
__device__ __forceinline__ float bf2f(unsigned short h) {
    return __builtin_bit_cast(float, (unsigned)h << 16);
}

// ---------------------------------------------------------------------------
// One-shot setup: weight bf16 conversion (blocks 0..1535), pe table
// (1536..1543), packed qkv bias (1544..1549).
__global__ void setup_all(const float* __restrict__ Wq, const float* __restrict__ Wk,
                          const float* __restrict__ Wv, const float* __restrict__ Wo,
                          const float* __restrict__ W1, const float* __restrict__ W2,
                          const float* __restrict__ bq, const float* __restrict__ bk,
                          const float* __restrict__ bv,
                          unsigned short* __restrict__ wB, float* __restrict__ pe,
                          float* __restrict__ bqkv) {
    int b = blockIdx.x, tid = threadIdx.x;
    if (b < 1536) {
        int i4 = b * 256 + tid;              // vec4 index over 2x786432 elems
        int e = i4 * 4;
        int l = (e >= 786432) ? 1 : 0;
        int r = e - l * 786432;
        const float* src;
        int off;
        if (r < 262144) {                    // Wq|Wk|Wv|Wo, 65536 each
            int w = r >> 16;
            off = (l << 16) + (r & 65535);
            src = (w == 0) ? Wq : (w == 1) ? Wk : (w == 2) ? Wv : Wo;
        } else if (r < 524288) {
            off = l * 262144 + (r - 262144);
            src = W1;
        } else {
            off = l * 262144 + (r - 524288);
            src = W2;
        }
        float4 v = *(const float4*)(src + off);
        unsigned short* o = wB + (size_t)l * 786432 + r;
        o[0] = f2bf(v.x); o[1] = f2bf(v.y); o[2] = f2bf(v.z); o[3] = f2bf(v.w);
    } else if (b < 1544) {
        int idx = (b - 1536) * 256 + tid;    // 0..2047
        int t = idx >> 8, c = idx & 255;
        int i2 = c & ~1;
        float div = __expf((float)i2 * (-logf(10000.f) / 256.f));
        float ang = (float)t * div;
        pe[idx] = (c & 1) ? cosf(ang) : sinf(ang);
    } else {
        int j = (b - 1544) * 256 + tid;      // 0..1535
        int l = j / 768, i = j - l * 768;
        float v = (i < 256) ? bq[l * 256 + i] : (i < 512) ? bk[l * 256 + i - 256]
                                                          : bv[l * 256 + i - 512];
        bqkv[j] = v;
    }
}

// ---------------------------------------------------------------------------
// x (B,T,C,H,W) -> hb (n, t, c) bf16, with += pe[t,c].
__global__ __launch_bounds__(256) void transpose_in(const float* __restrict__ x,
                                                    const float* __restrict__ pe,
                                                    unsigned short* __restrict__ hb) {
    int bty = blockIdx.x;
    int y = bty % 48; int bt = bty / 48; int t = bt & 7; int b = bt >> 3;
    int c0 = blockIdx.y * 32, w0 = blockIdx.z * 32;
    __shared__ float tile[32][33];
    int tid = threadIdx.x;
    const float* xp = x + ((size_t)(b * 8 + t) * 256) * 2304 + (size_t)y * 48;
    int wl = tid & 31, cl8 = tid >> 5;
#pragma unroll
    for (int it = 0; it < 4; ++it) {
        int c = c0 + it * 8 + cl8;
        int w = w0 + wl;
        if (w < 48) tile[it * 8 + cl8][wl] = xp[(size_t)c * 2304 + w] + pe[t * 256 + c];
    }
    __syncthreads();
    int cl = tid & 31, wl8 = tid >> 5;
#pragma unroll
    for (int it = 0; it < 4; ++it) {
        int w = w0 + it * 8 + wl8;
        int c = c0 + cl;
        if (w < 48) {
            size_t n = (size_t)(b * 48 + y) * 48 + w;
            hb[(n * 8 + t) * 256 + c] = f2bf(tile[cl][it * 8 + wl8]);
        }
    }
}

// out (B,C,H,W) fp32 = hb[n, T-1, c]
__global__ __launch_bounds__(256) void transpose_out(const unsigned short* __restrict__ hb,
                                                     float* __restrict__ out) {
    int by = blockIdx.x; int y = by % 48, b = by / 48;
    int c0 = blockIdx.y * 32, w0 = blockIdx.z * 32;
    __shared__ float tile[32][33];
    int tid = threadIdx.x;
    int cl = tid & 31, wl8 = tid >> 5;
#pragma unroll
    for (int it = 0; it < 4; ++it) {
        int w = w0 + it * 8 + wl8;
        if (w < 48) {
            size_t n = (size_t)(b * 48 + y) * 48 + w;
            tile[it * 8 + wl8][cl] = bf2f(hb[n * 2048 + 1792 + c0 + cl]);
        }
    }
    __syncthreads();
    int wl = tid & 31, cl8 = tid >> 5;
#pragma unroll
    for (int it = 0; it < 4; ++it) {
        int c = c0 + it * 8 + cl8;
        int w = w0 + wl;
        if (w < 48)
            out[((size_t)(b * 256 + c) * 48 + y) * 48 + w] = tile[wl][it * 8 + cl8];
    }
}

// ---------------------------------------------------------------------------
// bf16 MFMA GEMM (R13-proven): 128x128 tile, BK=32, 32 KB double-buffer ->
// 4 blocks/CU AND counted vmcnt(4) pipelining; swizzle slot ^= (row>>1)&3
// both-sides; setprio around MFMA; XCD-swizzled grid; LDS-restaged C store.
template <int ACT>
__global__ __launch_bounds__(256) void mgemm(const unsigned short* __restrict__ A,
                                             const unsigned short* __restrict__ W,
                                             const float* __restrict__ bias,
                                             unsigned short* __restrict__ C,
                                             int M, int N, int K) {
    __shared__ char smem[36864];          // loop: 32 KB dbuf; epi: [128][144] bf16
    const int tid = threadIdx.x;
    int nwg = gridDim.x * gridDim.y;
    int orig = blockIdx.y * gridDim.x + blockIdx.x;
    int wg = (orig & 7) * (nwg >> 3) + (orig >> 3);
    int bx = wg % gridDim.x, by = wg / gridDim.x;
    const int m0 = by * 128, n0 = bx * 128;
    const int lane = tid & 63, wv = tid >> 6;
    const int wr = wv >> 1, wc = wv & 1;
    const int lr = lane & 15, lk = lane >> 4;

    f32x4 acc[4][4] = {};

    int so[2], srow[2], sseg[2];
#pragma unroll
    for (int it = 0; it < 2; ++it) {
        int o = it * 4096 + tid * 16;
        so[it] = o;
        srow[it] = o >> 6;
        sseg[it] = ((o >> 4) & 3) ^ ((srow[it] >> 1) & 3);
    }

    const int nt = K >> 5;
#pragma unroll
    for (int it = 0; it < 2; ++it)
        GLD_LDS16(W + (size_t)(n0 + srow[it]) * K + sseg[it] * 8, smem + 16384 + so[it]);
#pragma unroll
    for (int it = 0; it < 2; ++it)
        GLD_LDS16(A + (size_t)(m0 + srow[it]) * K + sseg[it] * 8, smem + so[it]);

    int cur = 0;
    for (int t = 0; t < nt; ++t) {
        char* Ac = smem + cur * 8192;
        char* Bc = smem + 16384 + cur * 8192;
        if (t + 1 < nt) {
            const int k1 = (t + 1) << 5;
            char* An = smem + (cur ^ 1) * 8192;
            char* Bn = smem + 16384 + (cur ^ 1) * 8192;
#pragma unroll
            for (int it = 0; it < 2; ++it)
                GLD_LDS16(W + (size_t)(n0 + srow[it]) * K + k1 + sseg[it] * 8, Bn + so[it]);
#pragma unroll
            for (int it = 0; it < 2; ++it)
                GLD_LDS16(A + (size_t)(m0 + srow[it]) * K + k1 + sseg[it] * 8, An + so[it]);
            asm volatile("s_waitcnt vmcnt(4)" ::: "memory");
        } else {
            asm volatile("s_waitcnt vmcnt(0)" ::: "memory");
        }
        __builtin_amdgcn_s_barrier();
        __builtin_amdgcn_s_setprio(1);
        {
            bf16x8 fA[4], fB[4];
#pragma unroll
            for (int f = 0; f < 4; ++f) {
                int row = wr * 64 + f * 16 + lr;
                fA[f] = *(const bf16x8*)(Ac + row * 64 + ((lk ^ ((row >> 1) & 3)) << 4));
                int col = wc * 64 + f * 16 + lr;
                fB[f] = *(const bf16x8*)(Bc + col * 64 + ((lk ^ ((col >> 1) & 3)) << 4));
            }
#pragma unroll
            for (int fi = 0; fi < 4; ++fi)
#pragma unroll
                for (int fj = 0; fj < 4; ++fj)
                    acc[fi][fj] = __builtin_amdgcn_mfma_f32_16x16x32_bf16(
                        fA[fi], fB[fj], acc[fi][fj], 0, 0, 0);
        }
        __builtin_amdgcn_s_setprio(0);
        __builtin_amdgcn_s_barrier();
        cur ^= 1;
    }

    unsigned short* S = (unsigned short*)smem;
#pragma unroll
    for (int fi = 0; fi < 4; ++fi) {
        int rl = wr * 64 + fi * 16 + lk * 4;
#pragma unroll
        for (int fj = 0; fj < 4; ++fj) {
            int cl = wc * 64 + fj * 16 + lr;
            float bv = bias[n0 + cl];
#pragma unroll
            for (int r = 0; r < 4; ++r) {
                float v = acc[fi][fj][r] + bv;
                if (ACT) v = 0.5f * v * (1.0f + erff(v * 0.70710678118654752f));
                S[(rl + r) * 144 + cl] = f2bf(v);
            }
        }
    }
    __syncthreads();
#pragma unroll
    for (int it = 0; it < 8; ++it) {
        int idx = it * 256 + tid;
        int row = idx >> 4, c8 = (idx & 15) * 8;
        bf16x8 v = *(const bf16x8*)&S[row * 144 + c8];
        *(bf16x8*)&C[(size_t)(m0 + row) * N + n0 + c8] = v;
    }
}

// ---------------------------------------------------------------------------
// Streaming residual + LayerNorm on the bf16 carrier:
//   z = hb + c (fp32 math);  hb = bf16( (z-mean)/sqrt(var+eps)*g + be )
// One wave per 256-wide row, 4 rows per block, coalesced bf16x4 traffic.
__global__ __launch_bounds__(256) void resln(const unsigned short* __restrict__ c,
                                             unsigned short* __restrict__ hb,
                                             const float* __restrict__ g,
                                             const float* __restrict__ be) {
    int wv = threadIdx.x >> 6, lane = threadIdx.x & 63;
    size_t row = (size_t)blockIdx.x * 4 + wv;
    size_t off = row * 256 + lane * 4;
    bf16x4 hv = *(const bf16x4*)&hb[off];
    bf16x4 cv = *(const bf16x4*)&c[off];
    float4 z = {bf2f((unsigned short)hv[0]) + bf2f((unsigned short)cv[0]),
                bf2f((unsigned short)hv[1]) + bf2f((unsigned short)cv[1]),
                bf2f((unsigned short)hv[2]) + bf2f((unsigned short)cv[2]),
                bf2f((unsigned short)hv[3]) + bf2f((unsigned short)cv[3])};
    float s = z.x + z.y + z.z + z.w;
    float sq = z.x * z.x + z.y * z.y + z.z * z.z + z.w * z.w;
#pragma unroll
    for (int d = 1; d < 64; d <<= 1) {
        s += __shfl_xor(s, d);
        sq += __shfl_xor(sq, d);
    }
    float mean = s * (1.f / 256.f);
    float var = sq * (1.f / 256.f) - mean * mean;   // biased var
    float inv = 1.0f / sqrtf(var + 1e-5f);
    float4 gv = *(const float4*)&g[lane * 4];
    float4 bv = *(const float4*)&be[lane * 4];
    bf16x4 ob;
    ob[0] = (short)f2bf((z.x - mean) * inv * gv.x + bv.x);
    ob[1] = (short)f2bf((z.y - mean) * inv * gv.y + bv.y);
    ob[2] = (short)f2bf((z.z - mean) * inv * gv.z + bv.z);
    ob[3] = (short)f2bf((z.w - mean) * inv * gv.w + bv.w);
    *(bf16x4*)&hb[off] = ob;
}

// ---------------------------------------------------------------------------
// Causal MHSA: qkv packed bf16 [row][768] (q|k|v), ctx out bf16 [row][256].
__global__ __launch_bounds__(256) void attn_kernel(const unsigned short* __restrict__ qkv,
                                                   unsigned short* __restrict__ ctx) {
    __shared__ float Qs[8 * 260], Ks[8 * 260], Vs[8 * 260];
    int n = blockIdx.x;
    int tid = threadIdx.x;
    size_t base = (size_t)n * 6144;             // 8*768
#pragma unroll
    for (int it = 0; it < 6; ++it) {
        int i4 = it * 256 + tid;                // 0..1535
        int t = i4 / 192;
        int c4 = (i4 - t * 192) * 4;            // 0..764, mult of 4
        const unsigned short* p = qkv + base + (size_t)t * 768 + c4;
        float4 f = {bf2f(p[0]), bf2f(p[1]), bf2f(p[2]), bf2f(p[3])};
        float* dst = (c4 < 256) ? &Qs[t * 260 + c4]
                   : (c4 < 512) ? &Ks[t * 260 + (c4 - 256)]
                                : &Vs[t * 260 + (c4 - 512)];
        *(float4*)dst = f;
    }
    __syncthreads();
    int wid = tid >> 6, lane = tid & 63;
    int t = lane >> 3, s = lane & 7;
    size_t obase = (size_t)n * 2048;
    for (int hh = wid; hh < 8; hh += 4) {
        float acc = 0.f;
        int qb = t * 260 + hh * 32, kb = s * 260 + hh * 32;
#pragma unroll
        for (int jj = 0; jj < 8; ++jj) {
            float4 qv = *(const float4*)&Qs[qb + jj * 4];
            float4 kv = *(const float4*)&Ks[kb + jj * 4];
            acc += qv.x * kv.x + qv.y * kv.y + qv.z * kv.z + qv.w * kv.w;
        }
        acc *= 0.17677669529663687f;            // 1/sqrt(32)
        if (s > t) acc = -1e30f;
        float m = acc;
        m = fmaxf(m, __shfl_xor(m, 1));
        m = fmaxf(m, __shfl_xor(m, 2));
        m = fmaxf(m, __shfl_xor(m, 4));
        float e = __expf(acc - m);
        float sum = e;
        sum += __shfl_xor(sum, 1);
        sum += __shfl_xor(sum, 2);
        sum += __shfl_xor(sum, 4);
        float p = e / sum;
        float a4[4] = {0.f, 0.f, 0.f, 0.f};
#pragma unroll
        for (int s2 = 0; s2 < 8; ++s2) {
            float ps = __shfl(p, (lane & ~7) | s2);
            int vb = s2 * 260 + hh * 32 + s;
#pragma unroll
            for (int r = 0; r < 4; ++r) a4[r] += ps * Vs[vb + 8 * r];
        }
#pragma unroll
        for (int r = 0; r < 4; ++r)
            ctx[obase + t * 256 + hh * 32 + s + 8 * r] = f2bf(a4[r]);
    }
}

// ---------------------------------------------------------------------------
extern "C" void kernel_launch(void* const* d_in, const int* in_sizes, int n_in,
                              void* d_out, int out_size, void* d_ws, size_t ws_size,
                              hipStream_t stream) {
    const float* x   = (const float*)d_in[0];
    const float* Wq  = (const float*)d_in[1];
    const float* bq  = (const float*)d_in[2];
    const float* Wk  = (const float*)d_in[3];
    const float* bk  = (const float*)d_in[4];
    const float* Wv  = (const float*)d_in[5];
    const float* bv  = (const float*)d_in[6];
    const float* Wo  = (const float*)d_in[7];
    const float* bo  = (const float*)d_in[8];
    const float* g1  = (const float*)d_in[9];
    const float* be1 = (const float*)d_in[10];
    const float* W1  = (const float*)d_in[11];
    const float* b1  = (const float*)d_in[12];
    const float* W2  = (const float*)d_in[13];
    const float* b2  = (const float*)d_in[14];
    const float* g2  = (const float*)d_in[15];
    const float* be2 = (const float*)d_in[16];

    // ---- workspace layout (bytes); end = 229,662,720 < proven 264.3 MB ----
    char* base = (char*)d_ws;
    const size_t O_PE = 0;                           // 16 KB reserved
    const size_t O_W  = 16384;                       // bf16 weights: 3,145,728
    const size_t O_BQ = O_W + 3145728;               // packed qkv bias (8 KB)
    const size_t O_HB = O_BQ + 8192;                 // hb bf16: 37,748,736
    const size_t O_P1 = O_HB + (size_t)TOK * 512;    // qkv/wo-out/f1o pool: 150,994,944
    const size_t O_CT = O_P1 + (size_t)TOK * 2048;   // ctx / f2-out: 37,748,736

    float*          pe   = (float*)(base + O_PE);
    unsigned short* wB   = (unsigned short*)(base + O_W);
    float*          bqkv = (float*)(base + O_BQ);
    unsigned short* hb   = (unsigned short*)(base + O_HB);
    unsigned short* p1   = (unsigned short*)(base + O_P1);
    unsigned short* ctxb = (unsigned short*)(base + O_CT);

    setup_all<<<1550, 256, 0, stream>>>(Wq, Wk, Wv, Wo, W1, W2, bq, bk, bv,
                                        wB, pe, bqkv);
    transpose_in<<<dim3(1536, 8, 2), 256, 0, stream>>>(x, pe, hb);

    const int gy = TOK / 128;                        // 576
    for (int l = 0; l < 2; ++l) {
        unsigned short* wqkv = wB + (size_t)l * 786432;
        unsigned short* wo   = wqkv + 196608;
        unsigned short* w1   = wqkv + 262144;
        unsigned short* w2   = wqkv + 524288;

        // fused qkv projection (N=768) -> p1
        mgemm<0><<<dim3(6, gy), 256, 0, stream>>>(hb, wqkv, bqkv + l * 768, p1, TOK, 768, 256);
        attn_kernel<<<SEQ, 256, 0, stream>>>(p1, ctxb);
        // Wo projection: reads ctx, writes wo-out into p1 (qkv dead)
        mgemm<0><<<dim3(2, gy), 256, 0, stream>>>(ctxb, wo, bo + l * 256, p1, TOK, 256, 256);
        resln<<<TOK / 4, 256, 0, stream>>>(p1, hb, g1 + l * 256, be1 + l * 256);
        // FFN up + GELU -> p1 (wo-out dead)
        mgemm<1><<<dim3(8, gy), 256, 0, stream>>>(hb, w1, b1 + l * 1024, p1, TOK, 1024, 256);
        // FFN down -> ctx slot (dead since wo)
        mgemm<0><<<dim3(2, gy), 256, 0, stream>>>(p1, w2, b2 + l * 256, ctxb, TOK, 256, 1024);
        resln<<<TOK / 4, 256, 0, stream>>>(ctxb, hb, g2 + l * 256, be2 + l * 256);
    }

    transpose_out<<<dim3(192, 8, 2), 256, 0, stream>>>(hb, (float*)d_out);
}